// Round 12
// baseline (491.857 us; speedup 1.0000x reference)
//
#include <hip/hip_runtime.h>

#define SS 192
#define DD 512
#define DFF 2048
#define NROW 12288            // 64*192 rows per tensor
#define EPSV 1e-5f

using bf16x8 = __attribute__((ext_vector_type(8))) __bf16;
using f32x4  = __attribute__((ext_vector_type(4))) float;

__device__ inline unsigned short f2bf(float f) {
    unsigned u = __float_as_uint(f);
    unsigned r = (u + 0x7FFFu + ((u >> 16) & 1u)) >> 16;
    return (unsigned short)r;
}
__device__ inline float bf2f(unsigned short h) {
    return __uint_as_float(((unsigned)h) << 16);
}
// monotonic float<->uint for atomicMax on floats (incl. negatives)
__device__ inline unsigned f2mono(float f) {
    unsigned u = __float_as_uint(f);
    return u ^ ((unsigned)((int)u >> 31) | 0x80000000u);
}
__device__ inline float mono2f(unsigned u) {
    unsigned b = (u & 0x80000000u) ? (u ^ 0x80000000u) : ~u;
    return __uint_as_float(b);
}
#define ENC_NEGINF 0x007FFFFFu

// async global->LDS, 16B per lane. dst must be wave-uniform; src is per-lane.
#define GLL16(g, l) __builtin_amdgcn_global_load_lds( \
    (const __attribute__((address_space(1))) void*)(g), \
    (__attribute__((address_space(3))) void*)(l), 16, 0, 0)

template<int NW>
__device__ inline float blockReduceSum(float v) {
    __shared__ float red[NW];
    #pragma unroll
    for (int o = 32; o > 0; o >>= 1) v += __shfl_down(v, o);
    int w = threadIdx.x >> 6;
    __syncthreads();
    if ((threadIdx.x & 63) == 0) red[w] = v;
    __syncthreads();
    if (threadIdx.x == 0) {
        float t = 0;
        #pragma unroll
        for (int i = 0; i < NW; i++) t += red[i];
        red[0] = t;
    }
    __syncthreads();
    return red[0];
}

// ---------------- K0: f32 -> bf16 convert (4 elems/thread) ----------------
__global__ void k_cvt(const float* __restrict__ src, unsigned short* __restrict__ dst) {
    int i = blockIdx.x * 256 + threadIdx.x;
    float4 v = ((const float4*)src)[i];
    unsigned short o[4] = { f2bf(v.x), f2bf(v.y), f2bf(v.z), f2bf(v.w) };
    ((uint2*)dst)[i] = *(uint2*)o;
}

// ---------------- K2: sigmoid(score_embed) ----------------
__global__ void k_sig(const float* __restrict__ se, float* __restrict__ sig) {
    int i = blockIdx.x * 256 + threadIdx.x;   // grid 144*256 = 36864 exact
    sig[i] = 1.0f / (1.0f + __expf(-se[i]));
}

// ---------------- K2b: rowsum of W2 ----------------
__global__ void k_rowsum(const float* __restrict__ W2, float* __restrict__ rowsum) {
    int f = blockIdx.x * 256 + threadIdx.x;   // 8 blocks -> 2048
    float s = 0.f;
    for (int i = 0; i < SS; i++) s += W2[(size_t)f * SS + i];
    rowsum[f] = s;
}

// ---------------- K1: projection GEMM  P = Xbf @ W1bf.T + b1 -> bf16 ----------------
// M=24576, N=512, K=512. tile 128x128, BK=32. 3-buffer counted-vmcnt, FULLY UNROLLED.
__global__ __launch_bounds__(256) void k_proj(
    const unsigned short* __restrict__ xbf, const unsigned short* __restrict__ w1bf,
    const float* __restrict__ b1, unsigned short* __restrict__ outQK)
{
    __shared__ unsigned short sA[3][128 * 32];
    __shared__ unsigned short sB[3][128 * 32];
    const int tid = threadIdx.x;
    const int lane = tid & 63;
    const int w = tid >> 6;
    const int m0 = blockIdx.x * 128;
    const int n0 = blockIdx.y * 128;
    const int wm = (w >> 1) * 64, wn = (w & 1) * 64;

    f32x4 acc[4][4] = {};

    const int sr  = lane >> 2;                            // row within 16-block
    const int scg = (lane & 3) ^ ((lane >> 3) & 3);       // swizzled src colgroup
    const unsigned short* Ab = xbf  + (size_t)m0 * DD;
    const unsigned short* Bb = w1bf + (size_t)n0 * DD;
    // per-lane global src base for staging (row advances with k0 only)
    const unsigned short* AsrcB = Ab + (size_t)(w * 2 * 16 + sr) * DD + scg * 8;
    const unsigned short* BsrcB = Bb + (size_t)(w * 2 * 16 + sr) * DD + scg * 8;

    const int l16 = lane & 15, g = lane >> 4;
    const int cswz = ((g ^ ((l16 >> 1) & 3))) * 8;        // shorts

    #pragma unroll
    for (int pt = 0; pt < 2; pt++) {
        #pragma unroll
        for (int i = 0; i < 2; i++) {
            int rb = w * 2 + i;
            GLL16(AsrcB + (size_t)i * 16 * DD + pt * 32, &sA[pt][rb * 512]);
            GLL16(BsrcB + (size_t)i * 16 * DD + pt * 32, &sB[pt][rb * 512]);
        }
    }

    #pragma unroll
    for (int t = 0; t < 16; t++) {
        if (t < 15) asm volatile("s_waitcnt vmcnt(4)" ::: "memory");
        else        asm volatile("s_waitcnt vmcnt(0)" ::: "memory");
        __builtin_amdgcn_s_barrier();
        if (t + 2 < 16) {
            const int buf = (t + 2) % 3;       // compile-time after unroll
            const int k0  = (t + 2) * 32;
            #pragma unroll
            for (int i = 0; i < 2; i++) {
                int rb = w * 2 + i;
                GLL16(AsrcB + (size_t)i * 16 * DD + k0, &sA[buf][rb * 512]);
                GLL16(BsrcB + (size_t)i * 16 * DD + k0, &sB[buf][rb * 512]);
            }
        }
        const int cur = t % 3;
        const unsigned short* aBase = &sA[cur][(wm + l16) * 32 + cswz];
        const unsigned short* bBase = &sB[cur][(wn + l16) * 32 + cswz];
        bf16x8 af[4];
        #pragma unroll
        for (int mi = 0; mi < 4; mi++) af[mi] = *(const bf16x8*)(aBase + mi * 512);
        __builtin_amdgcn_s_setprio(1);
        #pragma unroll
        for (int ni = 0; ni < 4; ni++) {
            bf16x8 bfr = *(const bf16x8*)(bBase + ni * 512);
            #pragma unroll
            for (int mi = 0; mi < 4; mi++)
                acc[mi][ni] = __builtin_amdgcn_mfma_f32_16x16x32_bf16(af[mi], bfr, acc[mi][ni], 0, 0, 0);
        }
        __builtin_amdgcn_s_setprio(0);
    }

    const int rg = lane >> 4;
    #pragma unroll
    for (int ni = 0; ni < 4; ni++) {
        int e = n0 + wn + ni * 16 + l16;
        float bias = b1[e];
        #pragma unroll
        for (int mi = 0; mi < 4; mi++) {
            #pragma unroll
            for (int r = 0; r < 4; r++) {
                int row = m0 + wm + mi * 16 + rg * 4 + r;
                outQK[(size_t)row * DD + e] = f2bf(acc[mi][ni][r] + bias);
            }
        }
    }
}

// ---------------- K3: per-(q,k) score tile + sigmoid scale + dual max-pool + BN1 partial ----
// 16 waves (1024 thr), wave tile 48x48 (acc[3][3]=36 AGPR). 3-slot counted-vmcnt pipeline
// (R7-proven). BN1 partial is BARRIER-FREE: per-wave shfl reduce in waves 0-2 only.
__global__ __launch_bounds__(1024, 4) void k_score(
    const unsigned short* __restrict__ qB,
    const unsigned short* __restrict__ kB,
    const float* __restrict__ sig,
    float* __restrict__ pooled,
    float* __restrict__ bn1)
{
    __shared__ unsigned short sA[3][192 * 32];   // key rows (s)
    __shared__ unsigned short sB[3][192 * 32];   // query rows (t)
    __shared__ unsigned maxT[192];
    __shared__ unsigned maxS[192];

    const int tid = threadIdx.x;
    const int p = blockIdx.x;
    const int q = p >> 6, kk = p & 63;
    const unsigned short* Ab = kB + (size_t)kk * SS * DD;
    const unsigned short* Bb = qB + (size_t)q * SS * DD;

    if (tid < 192) { maxT[tid] = ENC_NEGINF; maxS[tid] = ENC_NEGINF; }

    const int lane = tid & 63, w = tid >> 6;     // w = 0..15
    const int wsr = (w >> 2) * 48;   // wave s-offset: 0,48,96,144
    const int wtc = (w & 3) * 48;    // wave t-offset: 0,48,96,144

    f32x4 acc[3][3] = {};

    // staging: waves 0-5 stage A (key, groups 0..11), waves 6-11 stage B (query, groups 0..11)
    const int sr  = lane >> 2;
    const int scg = (lane & 3) ^ ((lane >> 3) & 3);
    const bool stager = (w < 12);
    const bool isA = (w < 6);
    const int wg = (isA ? w : (w - 6)) * 2;      // first row-group (0,2,..,10)
    const unsigned short* srcB = (isA ? Ab : Bb) + (size_t)(wg * 16 + sr) * DD + scg * 8;
    unsigned short* dst0 = isA ? &sA[0][0] : &sB[0][0];

    const int l16 = lane & 15, g = lane >> 4;
    const int cswz = ((g ^ ((l16 >> 1) & 3))) * 8;

    if (stager) {
        #pragma unroll
        for (int pt = 0; pt < 2; pt++) {
            #pragma unroll
            for (int i = 0; i < 2; i++)
                GLL16(srcB + (size_t)i * 16 * DD + pt * 32, dst0 + pt * (192 * 32) + (wg + i) * 512);
        }
    }

    #pragma unroll
    for (int t = 0; t < 16; t++) {
        if (t < 15) asm volatile("s_waitcnt vmcnt(2)" ::: "memory");
        else        asm volatile("s_waitcnt vmcnt(0)" ::: "memory");
        __builtin_amdgcn_s_barrier();
        if (t + 2 < 16 && stager) {
            const int buf = (t + 2) % 3;         // compile-time after unroll
            const int k0  = (t + 2) * 32;
            #pragma unroll
            for (int i = 0; i < 2; i++)
                GLL16(srcB + (size_t)i * 16 * DD + k0, dst0 + buf * (192 * 32) + (wg + i) * 512);
        }
        const int cur = t % 3;
        const unsigned short* aBase = &sA[cur][(wsr + l16) * 32 + cswz];
        const unsigned short* bBase = &sB[cur][(wtc + l16) * 32 + cswz];
        bf16x8 af[3];
        #pragma unroll
        for (int mi = 0; mi < 3; mi++) af[mi] = *(const bf16x8*)(aBase + mi * 512);
        __builtin_amdgcn_s_setprio(1);
        #pragma unroll
        for (int ni = 0; ni < 3; ni++) {
            bf16x8 bfr = *(const bf16x8*)(bBase + ni * 512);
            #pragma unroll
            for (int mi = 0; mi < 3; mi++)
                acc[mi][ni] = __builtin_amdgcn_mfma_f32_16x16x32_bf16(af[mi], bfr, acc[mi][ni], 0, 0, 0);
        }
        __builtin_amdgcn_s_setprio(0);
    }

    const int rg = lane >> 4;

    // scale by sigmoid(score_embed)[s][t]
    #pragma unroll
    for (int mi = 0; mi < 3; mi++) {
        #pragma unroll
        for (int r = 0; r < 4; r++) {
            int s = wsr + mi * 16 + rg * 4 + r;
            const float* srow = sig + (size_t)s * SS + wtc;
            #pragma unroll
            for (int ni = 0; ni < 3; ni++)
                acc[mi][ni][r] *= srow[ni * 16 + l16];
        }
    }

    // column max over s (-> maxT indexed by t)
    #pragma unroll
    for (int ni = 0; ni < 3; ni++) {
        float cm = -INFINITY;
        #pragma unroll
        for (int mi = 0; mi < 3; mi++)
            #pragma unroll
            for (int r = 0; r < 4; r++)
                cm = fmaxf(cm, acc[mi][ni][r]);
        cm = fmaxf(cm, __shfl_xor(cm, 16));
        cm = fmaxf(cm, __shfl_xor(cm, 32));
        if (lane < 16) atomicMax(&maxT[wtc + ni * 16 + lane], f2mono(cm));
    }
    // row max over t (-> maxS indexed by s)
    #pragma unroll
    for (int mi = 0; mi < 3; mi++) {
        #pragma unroll
        for (int r = 0; r < 4; r++) {
            float rm = -INFINITY;
            #pragma unroll
            for (int ni = 0; ni < 3; ni++) rm = fmaxf(rm, acc[mi][ni][r]);
            rm = fmaxf(rm, __shfl_xor(rm, 1));
            rm = fmaxf(rm, __shfl_xor(rm, 2));
            rm = fmaxf(rm, __shfl_xor(rm, 4));
            rm = fmaxf(rm, __shfl_xor(rm, 8));
            if ((lane & 15) == 0)
                atomicMax(&maxS[wsr + mi * 16 + rg * 4 + r], f2mono(rm));
        }
    }
    __syncthreads();
    // epilogue: pooled write + barrier-free BN1 partial (waves 0-2 = tid<192 only)
    if (tid < 192) {
        float v1 = mono2f(maxT[tid]);
        float v2 = mono2f(maxS[tid]);
        float* out = pooled + (size_t)p * 384;
        out[tid]       = v1;
        out[192 + tid] = v2;
        float s_  = v1 + v2;
        float ss_ = v1 * v1 + v2 * v2;
        #pragma unroll
        for (int o = 32; o > 0; o >>= 1) {
            s_  += __shfl_down(s_, o);
            ss_ += __shfl_down(ss_, o);
        }
        if (lane == 0) {
            atomicAdd(&bn1[0], s_);
            atomicAdd(&bn1[1], ss_);
        }
    }
}

// ---------------- K5: z = a1*(x @ W2.T) + c1*rowsumW2 + b2 (bf16) + fused col-stats ------
// M=8192, N=2048, K=192. tile 128x128, BK=32 (6 steps).
__global__ __launch_bounds__(256) void k_w2(
    const float* __restrict__ x, const float* __restrict__ W2,
    const float* __restrict__ b2, const float* __restrict__ rowsum,
    const float* __restrict__ bn1, const float* __restrict__ g1,
    const float* __restrict__ be1, unsigned short* __restrict__ z,
    float* __restrict__ cs, float* __restrict__ css)
{
    __shared__ unsigned short lA[128][40];
    __shared__ unsigned short lB[128][40];
    const int tid = threadIdx.x;
    const int lane = tid & 63;
    const int w = tid >> 6;
    const int m0 = blockIdx.x * 128;
    const int n0 = blockIdx.y * 128;
    const int wm = (w >> 1) * 64, wn = (w & 1) * 64;

    f32x4 acc[4][4] = {};
    const int srow = tid >> 1;
    const int scol = (tid & 1) * 16;
    const float* Asrc = x  + (size_t)(m0 + srow) * SS;
    const float* Bsrc = W2 + (size_t)(n0 + srow) * SS;

    for (int k0 = 0; k0 < SS; k0 += 32) {
        {
            unsigned short tmp[16];
            const float4* s4 = (const float4*)(Asrc + k0 + scol);
            #pragma unroll
            for (int i = 0; i < 4; i++) {
                float4 v = s4[i];
                tmp[i*4+0] = f2bf(v.x); tmp[i*4+1] = f2bf(v.y);
                tmp[i*4+2] = f2bf(v.z); tmp[i*4+3] = f2bf(v.w);
            }
            *(uint4*)(&lA[srow][scol])     = *(uint4*)(&tmp[0]);
            *(uint4*)(&lA[srow][scol + 8]) = *(uint4*)(&tmp[8]);
            const float4* t4 = (const float4*)(Bsrc + k0 + scol);
            #pragma unroll
            for (int i = 0; i < 4; i++) {
                float4 v = t4[i];
                tmp[i*4+0] = f2bf(v.x); tmp[i*4+1] = f2bf(v.y);
                tmp[i*4+2] = f2bf(v.z); tmp[i*4+3] = f2bf(v.w);
            }
            *(uint4*)(&lB[srow][scol])     = *(uint4*)(&tmp[0]);
            *(uint4*)(&lB[srow][scol + 8]) = *(uint4*)(&tmp[8]);
        }
        __syncthreads();
        const int l16 = lane & 15, kg = (lane >> 4) * 8;
        bf16x8 af[4];
        #pragma unroll
        for (int mi = 0; mi < 4; mi++)
            af[mi] = *(const bf16x8*)(&lA[wm + mi*16 + l16][kg]);
        #pragma unroll
        for (int ni = 0; ni < 4; ni++) {
            bf16x8 bfr = *(const bf16x8*)(&lB[wn + ni*16 + l16][kg]);
            #pragma unroll
            for (int mi = 0; mi < 4; mi++)
                acc[mi][ni] = __builtin_amdgcn_mfma_f32_16x16x32_bf16(af[mi], bfr, acc[mi][ni], 0, 0, 0);
        }
        __syncthreads();
    }

    const float n1 = 8192.0f * 192.0f;
    const float m1 = bn1[0] / n1;
    const float v1 = bn1[1] / n1 - m1 * m1;
    const float a1 = g1[0] * rsqrtf(v1 + EPSV);
    const float c1 = be1[0] - m1 * a1;

    // fused per-column stats (replaces k_colstat): LDS reduce then 1 atomic/col
    float* colsum = (float*)&lA[0][0];         // [128]
    float* colssq = colsum + 128;              // [128]
    if (tid < 128) { colsum[tid] = 0.f; colssq[tid] = 0.f; }
    __syncthreads();

    const int l16 = lane & 15, rg = lane >> 4;
    #pragma unroll
    for (int ni = 0; ni < 4; ni++) {
        int lc = wn + ni*16 + l16;
        int f = n0 + lc;
        float add = c1 * rowsum[f] + b2[f];
        float s_ = 0.f, ss_ = 0.f;
        #pragma unroll
        for (int mi = 0; mi < 4; mi++) {
            #pragma unroll
            for (int r = 0; r < 4; r++) {
                int row = m0 + wm + mi*16 + rg*4 + r;
                float y = a1 * acc[mi][ni][r] + add;
                z[(size_t)row * DFF + f] = f2bf(y);
                s_ += y; ss_ += y * y;
            }
        }
        atomicAdd(&colsum[lc], s_);
        atomicAdd(&colssq[lc], ss_);
    }
    __syncthreads();
    if (tid < 128) {
        atomicAdd(&cs[n0 + tid],  colsum[tid]);
        atomicAdd(&css[n0 + tid], colssq[tid]);
    }
}

// ---------------- K7: rowout = relu(BN2(z)) . W3 + b3  (wave per row, coef inline) -------
__global__ __launch_bounds__(256) void k_final_dot(
    const unsigned short* __restrict__ z, const float* __restrict__ cs,
    const float* __restrict__ css, const float* __restrict__ g2,
    const float* __restrict__ be2, const float* __restrict__ W3,
    const float* __restrict__ b3, float* __restrict__ rowout)
{
    const int lane = threadIdx.x & 63, w = threadIdx.x >> 6;
    // coefs for this lane's 32 cols, computed inline from stats (replaces k_coef)
    float4 av[4][2], cv[4][2], wv[4][2];
    #pragma unroll
    for (int c = 0; c < 4; c++) {
        int col = c * 512 + lane * 8;
        #pragma unroll
        for (int h = 0; h < 2; h++) {
            float4 csv  = *(const float4*)(cs  + col + 4*h);
            float4 cssv = *(const float4*)(css + col + 4*h);
            float4 g2v  = *(const float4*)(g2  + col + 4*h);
            float4 be2v = *(const float4*)(be2 + col + 4*h);
            wv[c][h]    = *(const float4*)(W3  + col + 4*h);
            float* mp = (float*)&csv; float* sp = (float*)&cssv;
            float* gp = (float*)&g2v; float* bp = (float*)&be2v;
            float* ap = (float*)&av[c][h]; float* cp = (float*)&cv[c][h];
            #pragma unroll
            for (int j = 0; j < 4; j++) {
                float m  = mp[j] * (1.0f / 8192.0f);
                float vr = sp[j] * (1.0f / 8192.0f) - m * m;
                float a  = gp[j] * rsqrtf(vr + EPSV);
                ap[j] = a;
                cp[j] = bp[j] - m * a;
            }
        }
    }
    const float bias = b3[0];
    int r0 = blockIdx.x * 16 + w * 4;          // 512 blocks
    #pragma unroll
    for (int rr = 0; rr < 4; rr++) {
        int row = r0 + rr;
        float sum = 0.f;
        #pragma unroll
        for (int c = 0; c < 4; c++) {
            uint4 v = *(const uint4*)(z + (size_t)row * DFF + c * 512 + lane * 8);
            unsigned short pv[8];
            *(uint4*)pv = v;
            #pragma unroll
            for (int j = 0; j < 8; j++) {
                float a = ((const float*)&av[c][j >> 2])[j & 3];
                float cc = ((const float*)&cv[c][j >> 2])[j & 3];
                float wf = ((const float*)&wv[c][j >> 2])[j & 3];
                float x = a * bf2f(pv[j]) + cc;
                sum += fmaxf(x, 0.f) * wf;
            }
        }
        #pragma unroll
        for (int o = 32; o > 0; o >>= 1) sum += __shfl_down(sum, o);
        if (lane == 0) rowout[row] = sum + bias;
    }
}

// ---------------- K8: pair-sum + BN3 + output ----------------
__global__ __launch_bounds__(1024) void k_out(
    const float* __restrict__ rowout, const float* __restrict__ g3,
    const float* __restrict__ be3, float* __restrict__ out)
{
    float pv0, pv1, pv2, pv3;
    float s = 0.f, ss = 0.f;
    {
        int p0 = threadIdx.x;
        pv0 = rowout[2*p0] + rowout[2*p0+1];
        int p1 = 1024 + threadIdx.x;
        pv1 = rowout[2*p1] + rowout[2*p1+1];
        int p2 = 2048 + threadIdx.x;
        pv2 = rowout[2*p2] + rowout[2*p2+1];
        int p3 = 3072 + threadIdx.x;
        pv3 = rowout[2*p3] + rowout[2*p3+1];
        s = pv0 + pv1 + pv2 + pv3;
        ss = pv0*pv0 + pv1*pv1 + pv2*pv2 + pv3*pv3;
    }
    s  = blockReduceSum<16>(s);
    ss = blockReduceSum<16>(ss);
    float m  = s * (1.0f / 4096.0f);
    float vr = ss * (1.0f / 4096.0f) - m * m;
    float a  = g3[0] * rsqrtf(vr + EPSV);
    float c  = be3[0] - m * a;
    out[threadIdx.x]        = a * pv0 + c;
    out[1024 + threadIdx.x] = a * pv1 + c;
    out[2048 + threadIdx.x] = a * pv2 + c;
    out[3072 + threadIdx.x] = a * pv3 + c;
}

extern "C" void kernel_launch(void* const* d_in, const int* in_sizes, int n_in,
                              void* d_out, int out_size, void* d_ws, size_t ws_size,
                              hipStream_t stream)
{
    const float* tgt = (const float*)d_in[0];
    const float* mem = (const float*)d_in[1];
    const float* W1  = (const float*)d_in[2];
    const float* b1  = (const float*)d_in[3];
    const float* se  = (const float*)d_in[4];
    const float* g1  = (const float*)d_in[5];
    const float* be1 = (const float*)d_in[6];
    const float* W2  = (const float*)d_in[7];
    const float* b2  = (const float*)d_in[8];
    const float* g2  = (const float*)d_in[9];
    const float* be2 = (const float*)d_in[10];
    const float* W3  = (const float*)d_in[11];
    const float* b3  = (const float*)d_in[12];
    const float* g3  = (const float*)d_in[13];
    const float* be3 = (const float*)d_in[14];
    float* out = (float*)d_out;

    char* ws = (char*)d_ws;
    size_t off = 0;
    auto alloc = [&](size_t bytes) { void* p = ws + off; off += (bytes + 255) & ~(size_t)255; return p; };

    // region0: xbf (25.2 MB, used by k_proj) then reused as z (33.5 MB, from k_w2 on)
    char* region0 = (char*)alloc((size_t)8192 * DFF * 2);                  // 33.5 MB
    unsigned short* xbf = (unsigned short*)region0;                        // [24576][512] bf16
    unsigned short* z   = (unsigned short*)region0;                        // [8192][2048] bf16
    unsigned short* qk  = (unsigned short*)alloc((size_t)24576 * DD * 2);  // 25.2 MB (query | key)
    unsigned short* w1bf= (unsigned short*)alloc((size_t)DD * DD * 2);     // 0.5 MB
    float* sig          = (float*)alloc((size_t)SS * SS * 4);
    float* pooled       = (float*)alloc((size_t)4096 * 384 * 4);           // 6.3 MB
    float* rowsum       = (float*)alloc(DFF * 4);
    float* stats        = (float*)alloc((2 + 2 * DFF) * 4);                // bn1[2], cs[2048], css[2048]
    float* rowout       = (float*)alloc(8192 * 4);

    float* bn1 = stats;
    float* cs  = stats + 2;
    float* css = stats + 2 + DFF;

    hipMemsetAsync(stats, 0, (2 + 2 * DFF) * 4, stream);

    k_cvt<<<6144, 256, 0, stream>>>(tgt, xbf);                       // rows 0..12287
    k_cvt<<<6144, 256, 0, stream>>>(mem, xbf + (size_t)NROW * DD);   // rows 12288..24575
    k_cvt<<<256,  256, 0, stream>>>(W1, w1bf);
    k_sig<<<144, 256, 0, stream>>>(se, sig);
    k_rowsum<<<8, 256, 0, stream>>>(W2, rowsum);
    k_proj<<<dim3(192, 4), 256, 0, stream>>>(xbf, w1bf, b1, qk);
    k_score<<<4096, 1024, 0, stream>>>(qk, qk + (size_t)NROW * DD, sig, pooled, bn1);
    k_w2<<<dim3(64, 16), 256, 0, stream>>>(pooled, W2, b2, rowsum, bn1, g1, be1, z, cs, css);
    k_final_dot<<<512, 256, 0, stream>>>(z, cs, css, g2, be2, W3, b3, rowout);
    k_out<<<1, 1024, 0, stream>>>(rowout, g3, be3, out);
}

// Round 13
// 329.427 us; speedup vs baseline: 1.4931x; 1.4931x over previous
//
#include <hip/hip_runtime.h>

#define SS 192
#define DD 512
#define DFF 2048
#define NROW 12288            // 64*192 rows per tensor
#define EPSV 1e-5f

using bf16x8 = __attribute__((ext_vector_type(8))) __bf16;
using f32x4  = __attribute__((ext_vector_type(4))) float;

__device__ inline unsigned short f2bf(float f) {
    unsigned u = __float_as_uint(f);
    unsigned r = (u + 0x7FFFu + ((u >> 16) & 1u)) >> 16;
    return (unsigned short)r;
}
__device__ inline float bf2f(unsigned short h) {
    return __uint_as_float(((unsigned)h) << 16);
}
// monotonic float<->uint for atomicMax on floats (incl. negatives)
__device__ inline unsigned f2mono(float f) {
    unsigned u = __float_as_uint(f);
    return u ^ ((unsigned)((int)u >> 31) | 0x80000000u);
}
__device__ inline float mono2f(unsigned u) {
    unsigned b = (u & 0x80000000u) ? (u ^ 0x80000000u) : ~u;
    return __uint_as_float(b);
}
#define ENC_NEGINF 0x007FFFFFu

// async global->LDS, 16B per lane. dst must be wave-uniform; src is per-lane.
#define GLL16(g, l) __builtin_amdgcn_global_load_lds( \
    (const __attribute__((address_space(1))) void*)(g), \
    (__attribute__((address_space(3))) void*)(l), 16, 0, 0)

template<int NW>
__device__ inline float blockReduceSum(float v) {
    __shared__ float red[NW];
    #pragma unroll
    for (int o = 32; o > 0; o >>= 1) v += __shfl_down(v, o);
    int w = threadIdx.x >> 6;
    __syncthreads();
    if ((threadIdx.x & 63) == 0) red[w] = v;
    __syncthreads();
    if (threadIdx.x == 0) {
        float t = 0;
        #pragma unroll
        for (int i = 0; i < NW; i++) t += red[i];
        red[0] = t;
    }
    __syncthreads();
    return red[0];
}

// ---------------- K0: f32 -> bf16 convert (4 elems/thread) ----------------
__global__ void k_cvt(const float* __restrict__ src, unsigned short* __restrict__ dst) {
    int i = blockIdx.x * 256 + threadIdx.x;
    float4 v = ((const float4*)src)[i];
    unsigned short o[4] = { f2bf(v.x), f2bf(v.y), f2bf(v.z), f2bf(v.w) };
    ((uint2*)dst)[i] = *(uint2*)o;
}

// ---------------- K2: sigmoid(score_embed) ----------------
__global__ void k_sig(const float* __restrict__ se, float* __restrict__ sig) {
    int i = blockIdx.x * 256 + threadIdx.x;   // grid 144*256 = 36864 exact
    sig[i] = 1.0f / (1.0f + __expf(-se[i]));
}

// ---------------- K2b: rowsum of W2 ----------------
__global__ void k_rowsum(const float* __restrict__ W2, float* __restrict__ rowsum) {
    int f = blockIdx.x * 256 + threadIdx.x;   // 8 blocks -> 2048
    float s = 0.f;
    for (int i = 0; i < SS; i++) s += W2[(size_t)f * SS + i];
    rowsum[f] = s;
}

// ---------------- K1: projection GEMM  P = Xbf @ W1bf.T + b1 -> bf16 ----------------
// M=24576, N=512, K=512. tile 128x128, BK=32. 3-buffer counted-vmcnt, FULLY UNROLLED.
__global__ __launch_bounds__(256) void k_proj(
    const unsigned short* __restrict__ xbf, const unsigned short* __restrict__ w1bf,
    const float* __restrict__ b1, unsigned short* __restrict__ outQK)
{
    __shared__ unsigned short sA[3][128 * 32];
    __shared__ unsigned short sB[3][128 * 32];
    const int tid = threadIdx.x;
    const int lane = tid & 63;
    const int w = tid >> 6;
    const int m0 = blockIdx.x * 128;
    const int n0 = blockIdx.y * 128;
    const int wm = (w >> 1) * 64, wn = (w & 1) * 64;

    f32x4 acc[4][4] = {};

    const int sr  = lane >> 2;                            // row within 16-block
    const int scg = (lane & 3) ^ ((lane >> 3) & 3);       // swizzled src colgroup
    const unsigned short* Ab = xbf  + (size_t)m0 * DD;
    const unsigned short* Bb = w1bf + (size_t)n0 * DD;
    // per-lane global src base for staging (row advances with k0 only)
    const unsigned short* AsrcB = Ab + (size_t)(w * 2 * 16 + sr) * DD + scg * 8;
    const unsigned short* BsrcB = Bb + (size_t)(w * 2 * 16 + sr) * DD + scg * 8;

    const int l16 = lane & 15, g = lane >> 4;
    const int cswz = ((g ^ ((l16 >> 1) & 3))) * 8;        // shorts

    #pragma unroll
    for (int pt = 0; pt < 2; pt++) {
        #pragma unroll
        for (int i = 0; i < 2; i++) {
            int rb = w * 2 + i;
            GLL16(AsrcB + (size_t)i * 16 * DD + pt * 32, &sA[pt][rb * 512]);
            GLL16(BsrcB + (size_t)i * 16 * DD + pt * 32, &sB[pt][rb * 512]);
        }
    }

    #pragma unroll
    for (int t = 0; t < 16; t++) {
        if (t < 15) asm volatile("s_waitcnt vmcnt(4)" ::: "memory");
        else        asm volatile("s_waitcnt vmcnt(0)" ::: "memory");
        __builtin_amdgcn_s_barrier();
        if (t + 2 < 16) {
            const int buf = (t + 2) % 3;       // compile-time after unroll
            const int k0  = (t + 2) * 32;
            #pragma unroll
            for (int i = 0; i < 2; i++) {
                int rb = w * 2 + i;
                GLL16(AsrcB + (size_t)i * 16 * DD + k0, &sA[buf][rb * 512]);
                GLL16(BsrcB + (size_t)i * 16 * DD + k0, &sB[buf][rb * 512]);
            }
        }
        const int cur = t % 3;
        const unsigned short* aBase = &sA[cur][(wm + l16) * 32 + cswz];
        const unsigned short* bBase = &sB[cur][(wn + l16) * 32 + cswz];
        bf16x8 af[4];
        #pragma unroll
        for (int mi = 0; mi < 4; mi++) af[mi] = *(const bf16x8*)(aBase + mi * 512);
        __builtin_amdgcn_s_setprio(1);
        #pragma unroll
        for (int ni = 0; ni < 4; ni++) {
            bf16x8 bfr = *(const bf16x8*)(bBase + ni * 512);
            #pragma unroll
            for (int mi = 0; mi < 4; mi++)
                acc[mi][ni] = __builtin_amdgcn_mfma_f32_16x16x32_bf16(af[mi], bfr, acc[mi][ni], 0, 0, 0);
        }
        __builtin_amdgcn_s_setprio(0);
    }

    const int rg = lane >> 4;
    #pragma unroll
    for (int ni = 0; ni < 4; ni++) {
        int e = n0 + wn + ni * 16 + l16;
        float bias = b1[e];
        #pragma unroll
        for (int mi = 0; mi < 4; mi++) {
            #pragma unroll
            for (int r = 0; r < 4; r++) {
                int row = m0 + wm + mi * 16 + rg * 4 + r;
                outQK[(size_t)row * DD + e] = f2bf(acc[mi][ni][r] + bias);
            }
        }
    }
}

// ---------------- K3: per-(q,k) score tile + sigmoid scale + dual max-pool ----------------
// 16 waves (1024 thr), wave tile 48x48 (acc[3][3]=36 AGPR, 4 waves/SIMD). 3-slot
// counted-vmcnt pipeline (R7-proven, pristine). No BN1 fusion (atomics serialize).
__global__ __launch_bounds__(1024, 4) void k_score(
    const unsigned short* __restrict__ qB,
    const unsigned short* __restrict__ kB,
    const float* __restrict__ sig,
    float* __restrict__ pooled)
{
    __shared__ unsigned short sA[3][192 * 32];   // key rows (s)
    __shared__ unsigned short sB[3][192 * 32];   // query rows (t)
    __shared__ unsigned maxT[192];
    __shared__ unsigned maxS[192];

    const int tid = threadIdx.x;
    const int p = blockIdx.x;
    const int q = p >> 6, kk = p & 63;
    const unsigned short* Ab = kB + (size_t)kk * SS * DD;
    const unsigned short* Bb = qB + (size_t)q * SS * DD;

    if (tid < 192) { maxT[tid] = ENC_NEGINF; maxS[tid] = ENC_NEGINF; }

    const int lane = tid & 63, w = tid >> 6;     // w = 0..15
    const int wsr = (w >> 2) * 48;   // wave s-offset: 0,48,96,144
    const int wtc = (w & 3) * 48;    // wave t-offset: 0,48,96,144

    f32x4 acc[3][3] = {};

    // staging: waves 0-5 stage A (key, groups 0..11), waves 6-11 stage B (query, groups 0..11)
    const int sr  = lane >> 2;
    const int scg = (lane & 3) ^ ((lane >> 3) & 3);
    const bool stager = (w < 12);
    const bool isA = (w < 6);
    const int wg = (isA ? w : (w - 6)) * 2;      // first row-group (0,2,..,10)
    const unsigned short* srcB = (isA ? Ab : Bb) + (size_t)(wg * 16 + sr) * DD + scg * 8;
    unsigned short* dst0 = isA ? &sA[0][0] : &sB[0][0];

    const int l16 = lane & 15, g = lane >> 4;
    const int cswz = ((g ^ ((l16 >> 1) & 3))) * 8;

    if (stager) {
        #pragma unroll
        for (int pt = 0; pt < 2; pt++) {
            #pragma unroll
            for (int i = 0; i < 2; i++)
                GLL16(srcB + (size_t)i * 16 * DD + pt * 32, dst0 + pt * (192 * 32) + (wg + i) * 512);
        }
    }

    #pragma unroll
    for (int t = 0; t < 16; t++) {
        if (t < 15) asm volatile("s_waitcnt vmcnt(2)" ::: "memory");
        else        asm volatile("s_waitcnt vmcnt(0)" ::: "memory");
        __builtin_amdgcn_s_barrier();
        if (t + 2 < 16 && stager) {
            const int buf = (t + 2) % 3;         // compile-time after unroll
            const int k0  = (t + 2) * 32;
            #pragma unroll
            for (int i = 0; i < 2; i++)
                GLL16(srcB + (size_t)i * 16 * DD + k0, dst0 + buf * (192 * 32) + (wg + i) * 512);
        }
        const int cur = t % 3;
        const unsigned short* aBase = &sA[cur][(wsr + l16) * 32 + cswz];
        const unsigned short* bBase = &sB[cur][(wtc + l16) * 32 + cswz];
        bf16x8 af[3];
        #pragma unroll
        for (int mi = 0; mi < 3; mi++) af[mi] = *(const bf16x8*)(aBase + mi * 512);
        __builtin_amdgcn_s_setprio(1);
        #pragma unroll
        for (int ni = 0; ni < 3; ni++) {
            bf16x8 bfr = *(const bf16x8*)(bBase + ni * 512);
            #pragma unroll
            for (int mi = 0; mi < 3; mi++)
                acc[mi][ni] = __builtin_amdgcn_mfma_f32_16x16x32_bf16(af[mi], bfr, acc[mi][ni], 0, 0, 0);
        }
        __builtin_amdgcn_s_setprio(0);
    }

    const int rg = lane >> 4;

    // scale by sigmoid(score_embed)[s][t]
    #pragma unroll
    for (int mi = 0; mi < 3; mi++) {
        #pragma unroll
        for (int r = 0; r < 4; r++) {
            int s = wsr + mi * 16 + rg * 4 + r;
            const float* srow = sig + (size_t)s * SS + wtc;
            #pragma unroll
            for (int ni = 0; ni < 3; ni++)
                acc[mi][ni][r] *= srow[ni * 16 + l16];
        }
    }

    // column max over s (-> maxT indexed by t)
    #pragma unroll
    for (int ni = 0; ni < 3; ni++) {
        float cm = -INFINITY;
        #pragma unroll
        for (int mi = 0; mi < 3; mi++)
            #pragma unroll
            for (int r = 0; r < 4; r++)
                cm = fmaxf(cm, acc[mi][ni][r]);
        cm = fmaxf(cm, __shfl_xor(cm, 16));
        cm = fmaxf(cm, __shfl_xor(cm, 32));
        if (lane < 16) atomicMax(&maxT[wtc + ni * 16 + lane], f2mono(cm));
    }
    // row max over t (-> maxS indexed by s)
    #pragma unroll
    for (int mi = 0; mi < 3; mi++) {
        #pragma unroll
        for (int r = 0; r < 4; r++) {
            float rm = -INFINITY;
            #pragma unroll
            for (int ni = 0; ni < 3; ni++) rm = fmaxf(rm, acc[mi][ni][r]);
            rm = fmaxf(rm, __shfl_xor(rm, 1));
            rm = fmaxf(rm, __shfl_xor(rm, 2));
            rm = fmaxf(rm, __shfl_xor(rm, 4));
            rm = fmaxf(rm, __shfl_xor(rm, 8));
            if ((lane & 15) == 0)
                atomicMax(&maxS[wsr + mi * 16 + rg * 4 + r], f2mono(rm));
        }
    }
    __syncthreads();
    float* out = pooled + (size_t)p * 384;
    if (tid < 192) {
        out[tid]       = mono2f(maxT[tid]);
        out[192 + tid] = mono2f(maxS[tid]);
    }
}

// ---------------- K4: BN1 global stats over pooled (separate; 384 atomics total) --------
__global__ __launch_bounds__(256) void k_bn1(const float* __restrict__ pooled, float* __restrict__ bn1) {
    float s = 0.f, ss = 0.f;
    size_t base = (size_t)blockIdx.x * 8192;   // 192 blocks * 8192 = 1572864 exact
    for (int i = 0; i < 32; i++) {
        float v = pooled[base + i * 256 + threadIdx.x];
        s += v; ss += v * v;
    }
    s  = blockReduceSum<4>(s);
    ss = blockReduceSum<4>(ss);
    if (threadIdx.x == 0) { atomicAdd(&bn1[0], s); atomicAdd(&bn1[1], ss); }
}

// ---------------- K5: z = a1*(x @ W2.T) + c1*rowsumW2 + b2 (bf16) + fused col-stats ------
// M=8192, N=2048, K=192. tile 128x128, BK=32 (6 steps).
__global__ __launch_bounds__(256) void k_w2(
    const float* __restrict__ x, const float* __restrict__ W2,
    const float* __restrict__ b2, const float* __restrict__ rowsum,
    const float* __restrict__ bn1, const float* __restrict__ g1,
    const float* __restrict__ be1, unsigned short* __restrict__ z,
    float* __restrict__ cs, float* __restrict__ css)
{
    __shared__ unsigned short lA[128][40];
    __shared__ unsigned short lB[128][40];
    const int tid = threadIdx.x;
    const int lane = tid & 63;
    const int w = tid >> 6;
    const int m0 = blockIdx.x * 128;
    const int n0 = blockIdx.y * 128;
    const int wm = (w >> 1) * 64, wn = (w & 1) * 64;

    f32x4 acc[4][4] = {};
    const int srow = tid >> 1;
    const int scol = (tid & 1) * 16;
    const float* Asrc = x  + (size_t)(m0 + srow) * SS;
    const float* Bsrc = W2 + (size_t)(n0 + srow) * SS;

    for (int k0 = 0; k0 < SS; k0 += 32) {
        {
            unsigned short tmp[16];
            const float4* s4 = (const float4*)(Asrc + k0 + scol);
            #pragma unroll
            for (int i = 0; i < 4; i++) {
                float4 v = s4[i];
                tmp[i*4+0] = f2bf(v.x); tmp[i*4+1] = f2bf(v.y);
                tmp[i*4+2] = f2bf(v.z); tmp[i*4+3] = f2bf(v.w);
            }
            *(uint4*)(&lA[srow][scol])     = *(uint4*)(&tmp[0]);
            *(uint4*)(&lA[srow][scol + 8]) = *(uint4*)(&tmp[8]);
            const float4* t4 = (const float4*)(Bsrc + k0 + scol);
            #pragma unroll
            for (int i = 0; i < 4; i++) {
                float4 v = t4[i];
                tmp[i*4+0] = f2bf(v.x); tmp[i*4+1] = f2bf(v.y);
                tmp[i*4+2] = f2bf(v.z); tmp[i*4+3] = f2bf(v.w);
            }
            *(uint4*)(&lB[srow][scol])     = *(uint4*)(&tmp[0]);
            *(uint4*)(&lB[srow][scol + 8]) = *(uint4*)(&tmp[8]);
        }
        __syncthreads();
        const int l16 = lane & 15, kg = (lane >> 4) * 8;
        bf16x8 af[4];
        #pragma unroll
        for (int mi = 0; mi < 4; mi++)
            af[mi] = *(const bf16x8*)(&lA[wm + mi*16 + l16][kg]);
        #pragma unroll
        for (int ni = 0; ni < 4; ni++) {
            bf16x8 bfr = *(const bf16x8*)(&lB[wn + ni*16 + l16][kg]);
            #pragma unroll
            for (int mi = 0; mi < 4; mi++)
                acc[mi][ni] = __builtin_amdgcn_mfma_f32_16x16x32_bf16(af[mi], bfr, acc[mi][ni], 0, 0, 0);
        }
        __syncthreads();
    }

    const float n1 = 8192.0f * 192.0f;
    const float m1 = bn1[0] / n1;
    const float v1 = bn1[1] / n1 - m1 * m1;
    const float a1 = g1[0] * rsqrtf(v1 + EPSV);
    const float c1 = be1[0] - m1 * a1;

    // fused per-column stats (replaces k_colstat): LDS reduce then 1 atomic/col
    float* colsum = (float*)&lA[0][0];         // [128]
    float* colssq = colsum + 128;              // [128]
    if (tid < 128) { colsum[tid] = 0.f; colssq[tid] = 0.f; }
    __syncthreads();

    const int l16 = lane & 15, rg = lane >> 4;
    #pragma unroll
    for (int ni = 0; ni < 4; ni++) {
        int lc = wn + ni*16 + l16;
        int f = n0 + lc;
        float add = c1 * rowsum[f] + b2[f];
        float s_ = 0.f, ss_ = 0.f;
        #pragma unroll
        for (int mi = 0; mi < 4; mi++) {
            #pragma unroll
            for (int r = 0; r < 4; r++) {
                int row = m0 + wm + mi*16 + rg*4 + r;
                float y = a1 * acc[mi][ni][r] + add;
                z[(size_t)row * DFF + f] = f2bf(y);
                s_ += y; ss_ += y * y;
            }
        }
        atomicAdd(&colsum[lc], s_);
        atomicAdd(&colssq[lc], ss_);
    }
    __syncthreads();
    if (tid < 128) {
        atomicAdd(&cs[n0 + tid],  colsum[tid]);
        atomicAdd(&css[n0 + tid], colssq[tid]);
    }
}

// ---------------- K7: rowout = relu(BN2(z)) . W3 + b3  (wave per row, coef inline) -------
__global__ __launch_bounds__(256) void k_final_dot(
    const unsigned short* __restrict__ z, const float* __restrict__ cs,
    const float* __restrict__ css, const float* __restrict__ g2,
    const float* __restrict__ be2, const float* __restrict__ W3,
    const float* __restrict__ b3, float* __restrict__ rowout)
{
    const int lane = threadIdx.x & 63, w = threadIdx.x >> 6;
    // coefs for this lane's 32 cols, computed inline from stats (replaces k_coef)
    float4 av[4][2], cv[4][2], wv[4][2];
    #pragma unroll
    for (int c = 0; c < 4; c++) {
        int col = c * 512 + lane * 8;
        #pragma unroll
        for (int h = 0; h < 2; h++) {
            float4 csv  = *(const float4*)(cs  + col + 4*h);
            float4 cssv = *(const float4*)(css + col + 4*h);
            float4 g2v  = *(const float4*)(g2  + col + 4*h);
            float4 be2v = *(const float4*)(be2 + col + 4*h);
            wv[c][h]    = *(const float4*)(W3  + col + 4*h);
            float* mp = (float*)&csv; float* sp = (float*)&cssv;
            float* gp = (float*)&g2v; float* bp = (float*)&be2v;
            float* ap = (float*)&av[c][h]; float* cp = (float*)&cv[c][h];
            #pragma unroll
            for (int j = 0; j < 4; j++) {
                float m  = mp[j] * (1.0f / 8192.0f);
                float vr = sp[j] * (1.0f / 8192.0f) - m * m;
                float a  = gp[j] * rsqrtf(vr + EPSV);
                ap[j] = a;
                cp[j] = bp[j] - m * a;
            }
        }
    }
    const float bias = b3[0];
    int r0 = blockIdx.x * 16 + w * 4;          // 512 blocks
    #pragma unroll
    for (int rr = 0; rr < 4; rr++) {
        int row = r0 + rr;
        float sum = 0.f;
        #pragma unroll
        for (int c = 0; c < 4; c++) {
            uint4 v = *(const uint4*)(z + (size_t)row * DFF + c * 512 + lane * 8);
            unsigned short pv[8];
            *(uint4*)pv = v;
            #pragma unroll
            for (int j = 0; j < 8; j++) {
                float a = ((const float*)&av[c][j >> 2])[j & 3];
                float cc = ((const float*)&cv[c][j >> 2])[j & 3];
                float wf = ((const float*)&wv[c][j >> 2])[j & 3];
                float x = a * bf2f(pv[j]) + cc;
                sum += fmaxf(x, 0.f) * wf;
            }
        }
        #pragma unroll
        for (int o = 32; o > 0; o >>= 1) sum += __shfl_down(sum, o);
        if (lane == 0) rowout[row] = sum + bias;
    }
}

// ---------------- K8: pair-sum + BN3 + output ----------------
__global__ __launch_bounds__(1024) void k_out(
    const float* __restrict__ rowout, const float* __restrict__ g3,
    const float* __restrict__ be3, float* __restrict__ out)
{
    float pv0, pv1, pv2, pv3;
    float s = 0.f, ss = 0.f;
    {
        int p0 = threadIdx.x;
        pv0 = rowout[2*p0] + rowout[2*p0+1];
        int p1 = 1024 + threadIdx.x;
        pv1 = rowout[2*p1] + rowout[2*p1+1];
        int p2 = 2048 + threadIdx.x;
        pv2 = rowout[2*p2] + rowout[2*p2+1];
        int p3 = 3072 + threadIdx.x;
        pv3 = rowout[2*p3] + rowout[2*p3+1];
        s = pv0 + pv1 + pv2 + pv3;
        ss = pv0*pv0 + pv1*pv1 + pv2*pv2 + pv3*pv3;
    }
    s  = blockReduceSum<16>(s);
    ss = blockReduceSum<16>(ss);
    float m  = s * (1.0f / 4096.0f);
    float vr = ss * (1.0f / 4096.0f) - m * m;
    float a  = g3[0] * rsqrtf(vr + EPSV);
    float c  = be3[0] - m * a;
    out[threadIdx.x]        = a * pv0 + c;
    out[1024 + threadIdx.x] = a * pv1 + c;
    out[2048 + threadIdx.x] = a * pv2 + c;
    out[3072 + threadIdx.x] = a * pv3 + c;
}

extern "C" void kernel_launch(void* const* d_in, const int* in_sizes, int n_in,
                              void* d_out, int out_size, void* d_ws, size_t ws_size,
                              hipStream_t stream)
{
    const float* tgt = (const float*)d_in[0];
    const float* mem = (const float*)d_in[1];
    const float* W1  = (const float*)d_in[2];
    const float* b1  = (const float*)d_in[3];
    const float* se  = (const float*)d_in[4];
    const float* g1  = (const float*)d_in[5];
    const float* be1 = (const float*)d_in[6];
    const float* W2  = (const float*)d_in[7];
    const float* b2  = (const float*)d_in[8];
    const float* g2  = (const float*)d_in[9];
    const float* be2 = (const float*)d_in[10];
    const float* W3  = (const float*)d_in[11];
    const float* b3  = (const float*)d_in[12];
    const float* g3  = (const float*)d_in[13];
    const float* be3 = (const float*)d_in[14];
    float* out = (float*)d_out;

    char* ws = (char*)d_ws;
    size_t off = 0;
    auto alloc = [&](size_t bytes) { void* p = ws + off; off += (bytes + 255) & ~(size_t)255; return p; };

    // region0: xbf (25.2 MB, used by k_proj) then reused as z (33.5 MB, from k_w2 on)
    char* region0 = (char*)alloc((size_t)8192 * DFF * 2);                  // 33.5 MB
    unsigned short* xbf = (unsigned short*)region0;                        // [24576][512] bf16
    unsigned short* z   = (unsigned short*)region0;                        // [8192][2048] bf16
    unsigned short* qk  = (unsigned short*)alloc((size_t)24576 * DD * 2);  // 25.2 MB (query | key)
    unsigned short* w1bf= (unsigned short*)alloc((size_t)DD * DD * 2);     // 0.5 MB
    float* sig          = (float*)alloc((size_t)SS * SS * 4);
    float* pooled       = (float*)alloc((size_t)4096 * 384 * 4);           // 6.3 MB
    float* rowsum       = (float*)alloc(DFF * 4);
    float* stats        = (float*)alloc((2 + 2 * DFF) * 4);                // bn1[2], cs[2048], css[2048]
    float* rowout       = (float*)alloc(8192 * 4);

    float* bn1 = stats;
    float* cs  = stats + 2;
    float* css = stats + 2 + DFF;

    hipMemsetAsync(stats, 0, (2 + 2 * DFF) * 4, stream);

    k_cvt<<<6144, 256, 0, stream>>>(tgt, xbf);                       // rows 0..12287
    k_cvt<<<6144, 256, 0, stream>>>(mem, xbf + (size_t)NROW * DD);   // rows 12288..24575
    k_cvt<<<256,  256, 0, stream>>>(W1, w1bf);
    k_sig<<<144, 256, 0, stream>>>(se, sig);
    k_rowsum<<<8, 256, 0, stream>>>(W2, rowsum);
    k_proj<<<dim3(192, 4), 256, 0, stream>>>(xbf, w1bf, b1, qk);
    k_score<<<4096, 1024, 0, stream>>>(qk, qk + (size_t)NROW * DD, sig, pooled);
    k_bn1<<<192, 256, 0, stream>>>(pooled, bn1);
    k_w2<<<dim3(64, 16), 256, 0, stream>>>(pooled, W2, b2, rowsum, bn1, g1, be1, z, cs, css);
    k_final_dot<<<512, 256, 0, stream>>>(z, cs, css, g2, be2, W3, b3, rowout);
    k_out<<<1, 1024, 0, stream>>>(rowout, g3, be3, out);
}

// Round 14
// 314.909 us; speedup vs baseline: 1.5619x; 1.0461x over previous
//
#include <hip/hip_runtime.h>

#define SS 192
#define DD 512
#define DFF 2048
#define NROW 12288            // 64*192 rows per tensor
#define EPSV 1e-5f

using bf16x8 = __attribute__((ext_vector_type(8))) __bf16;
using f32x4  = __attribute__((ext_vector_type(4))) float;

__device__ inline unsigned short f2bf(float f) {
    unsigned u = __float_as_uint(f);
    unsigned r = (u + 0x7FFFu + ((u >> 16) & 1u)) >> 16;
    return (unsigned short)r;
}
__device__ inline float bf2f(unsigned short h) {
    return __uint_as_float(((unsigned)h) << 16);
}
// monotonic float<->uint for atomicMax on floats (incl. negatives)
__device__ inline unsigned f2mono(float f) {
    unsigned u = __float_as_uint(f);
    return u ^ ((unsigned)((int)u >> 31) | 0x80000000u);
}
__device__ inline float mono2f(unsigned u) {
    unsigned b = (u & 0x80000000u) ? (u ^ 0x80000000u) : ~u;
    return __uint_as_float(b);
}
#define ENC_NEGINF 0x007FFFFFu

// async global->LDS, 16B per lane. dst must be wave-uniform; src is per-lane.
#define GLL16(g, l) __builtin_amdgcn_global_load_lds( \
    (const __attribute__((address_space(1))) void*)(g), \
    (__attribute__((address_space(3))) void*)(l), 16, 0, 0)

template<int NW>
__device__ inline float blockReduceSum(float v) {
    __shared__ float red[NW];
    #pragma unroll
    for (int o = 32; o > 0; o >>= 1) v += __shfl_down(v, o);
    int w = threadIdx.x >> 6;
    __syncthreads();
    if ((threadIdx.x & 63) == 0) red[w] = v;
    __syncthreads();
    if (threadIdx.x == 0) {
        float t = 0;
        #pragma unroll
        for (int i = 0; i < NW; i++) t += red[i];
        red[0] = t;
    }
    __syncthreads();
    return red[0];
}

// ---------------- K0: tgt+mem f32 -> bf16 (one launch) ----------------
__global__ void k_cvt2(const float* __restrict__ a, const float* __restrict__ b,
                       unsigned short* __restrict__ dst) {
    int i = blockIdx.x * 256 + threadIdx.x;        // grid 12288 -> 3145728 quads
    const int half = NROW * DD / 4;                 // tgt quads
    const float* src = (i < half) ? a : b;
    int j = (i < half) ? i : i - half;
    float4 v = ((const float4*)src)[j];
    unsigned short o[4] = { f2bf(v.x), f2bf(v.y), f2bf(v.z), f2bf(v.w) };
    ((uint2*)dst)[i] = *(uint2*)o;
}

// ---------------- K1p: prep (W1 cvt | sigmoid | W2 rowsum | W2 cvt) one launch ---------
__global__ void k_prep(const float* __restrict__ W1, const float* __restrict__ se,
                       const float* __restrict__ W2,
                       unsigned short* __restrict__ w1bf, float* __restrict__ sig,
                       float* __restrict__ rowsum, unsigned short* __restrict__ w2bf) {
    int bid = blockIdx.x;
    if (bid < 256) {                                // W1: 262144 elems / 1024 = 256 blocks
        int i = bid * 256 + threadIdx.x;
        float4 v = ((const float4*)W1)[i];
        unsigned short o[4] = { f2bf(v.x), f2bf(v.y), f2bf(v.z), f2bf(v.w) };
        ((uint2*)w1bf)[i] = *(uint2*)o;
    } else if (bid < 400) {                         // sig: 36864 / 256 = 144 blocks
        int i = (bid - 256) * 256 + threadIdx.x;
        sig[i] = 1.0f / (1.0f + __expf(-se[i]));
    } else if (bid < 408) {                         // rowsum: 8 blocks
        int f = (bid - 400) * 256 + threadIdx.x;
        float s = 0.f;
        for (int i = 0; i < SS; i++) s += W2[(size_t)f * SS + i];
        rowsum[f] = s;
    } else {                                        // W2: 393216 elems / 1024 = 384 blocks
        int i = (bid - 408) * 256 + threadIdx.x;
        float4 v = ((const float4*)W2)[i];
        unsigned short o[4] = { f2bf(v.x), f2bf(v.y), f2bf(v.z), f2bf(v.w) };
        ((uint2*)w2bf)[i] = *(uint2*)o;
    }
}

// ---------------- K1: projection GEMM  P = Xbf @ W1bf.T + b1 -> bf16 ----------------
// M=24576, N=512, K=512. tile 128x128, BK=32. 3-buffer counted-vmcnt, FULLY UNROLLED.
__global__ __launch_bounds__(256) void k_proj(
    const unsigned short* __restrict__ xbf, const unsigned short* __restrict__ w1bf,
    const float* __restrict__ b1, unsigned short* __restrict__ outQK)
{
    __shared__ unsigned short sA[3][128 * 32];
    __shared__ unsigned short sB[3][128 * 32];
    const int tid = threadIdx.x;
    const int lane = tid & 63;
    const int w = tid >> 6;
    const int m0 = blockIdx.x * 128;
    const int n0 = blockIdx.y * 128;
    const int wm = (w >> 1) * 64, wn = (w & 1) * 64;

    f32x4 acc[4][4] = {};

    const int sr  = lane >> 2;                            // row within 16-block
    const int scg = (lane & 3) ^ ((lane >> 3) & 3);       // swizzled src colgroup
    const unsigned short* Ab = xbf  + (size_t)m0 * DD;
    const unsigned short* Bb = w1bf + (size_t)n0 * DD;
    const unsigned short* AsrcB = Ab + (size_t)(w * 2 * 16 + sr) * DD + scg * 8;
    const unsigned short* BsrcB = Bb + (size_t)(w * 2 * 16 + sr) * DD + scg * 8;

    const int l16 = lane & 15, g = lane >> 4;
    const int cswz = ((g ^ ((l16 >> 1) & 3))) * 8;        // shorts

    #pragma unroll
    for (int pt = 0; pt < 2; pt++) {
        #pragma unroll
        for (int i = 0; i < 2; i++) {
            int rb = w * 2 + i;
            GLL16(AsrcB + (size_t)i * 16 * DD + pt * 32, &sA[pt][rb * 512]);
            GLL16(BsrcB + (size_t)i * 16 * DD + pt * 32, &sB[pt][rb * 512]);
        }
    }

    #pragma unroll
    for (int t = 0; t < 16; t++) {
        if (t < 15) asm volatile("s_waitcnt vmcnt(4)" ::: "memory");
        else        asm volatile("s_waitcnt vmcnt(0)" ::: "memory");
        __builtin_amdgcn_s_barrier();
        if (t + 2 < 16) {
            const int buf = (t + 2) % 3;       // compile-time after unroll
            const int k0  = (t + 2) * 32;
            #pragma unroll
            for (int i = 0; i < 2; i++) {
                int rb = w * 2 + i;
                GLL16(AsrcB + (size_t)i * 16 * DD + k0, &sA[buf][rb * 512]);
                GLL16(BsrcB + (size_t)i * 16 * DD + k0, &sB[buf][rb * 512]);
            }
        }
        const int cur = t % 3;
        const unsigned short* aBase = &sA[cur][(wm + l16) * 32 + cswz];
        const unsigned short* bBase = &sB[cur][(wn + l16) * 32 + cswz];
        bf16x8 af[4];
        #pragma unroll
        for (int mi = 0; mi < 4; mi++) af[mi] = *(const bf16x8*)(aBase + mi * 512);
        __builtin_amdgcn_s_setprio(1);
        #pragma unroll
        for (int ni = 0; ni < 4; ni++) {
            bf16x8 bfr = *(const bf16x8*)(bBase + ni * 512);
            #pragma unroll
            for (int mi = 0; mi < 4; mi++)
                acc[mi][ni] = __builtin_amdgcn_mfma_f32_16x16x32_bf16(af[mi], bfr, acc[mi][ni], 0, 0, 0);
        }
        __builtin_amdgcn_s_setprio(0);
    }

    const int rg = lane >> 4;
    #pragma unroll
    for (int ni = 0; ni < 4; ni++) {
        int e = n0 + wn + ni * 16 + l16;
        float bias = b1[e];
        #pragma unroll
        for (int mi = 0; mi < 4; mi++) {
            #pragma unroll
            for (int r = 0; r < 4; r++) {
                int row = m0 + wm + mi * 16 + rg * 4 + r;
                outQK[(size_t)row * DD + e] = f2bf(acc[mi][ni][r] + bias);
            }
        }
    }
}

// ---------------- K3: per-(q,k) score tile + sigmoid scale + dual max-pool ----------------
// 16 waves (1024 thr), wave tile 48x48 (acc[3][3]=36 AGPR, 4 waves/SIMD). 3-slot
// counted-vmcnt pipeline (R7-proven, pristine). No BN1 fusion (atomics serialize).
__global__ __launch_bounds__(1024, 4) void k_score(
    const unsigned short* __restrict__ qB,
    const unsigned short* __restrict__ kB,
    const float* __restrict__ sig,
    float* __restrict__ pooled)
{
    __shared__ unsigned short sA[3][192 * 32];   // key rows (s)
    __shared__ unsigned short sB[3][192 * 32];   // query rows (t)
    __shared__ unsigned maxT[192];
    __shared__ unsigned maxS[192];

    const int tid = threadIdx.x;
    const int p = blockIdx.x;
    const int q = p >> 6, kk = p & 63;
    const unsigned short* Ab = kB + (size_t)kk * SS * DD;
    const unsigned short* Bb = qB + (size_t)q * SS * DD;

    if (tid < 192) { maxT[tid] = ENC_NEGINF; maxS[tid] = ENC_NEGINF; }

    const int lane = tid & 63, w = tid >> 6;     // w = 0..15
    const int wsr = (w >> 2) * 48;   // wave s-offset: 0,48,96,144
    const int wtc = (w & 3) * 48;    // wave t-offset: 0,48,96,144

    f32x4 acc[3][3] = {};

    const int sr  = lane >> 2;
    const int scg = (lane & 3) ^ ((lane >> 3) & 3);
    const bool stager = (w < 12);
    const bool isA = (w < 6);
    const int wg = (isA ? w : (w - 6)) * 2;      // first row-group (0,2,..,10)
    const unsigned short* srcB = (isA ? Ab : Bb) + (size_t)(wg * 16 + sr) * DD + scg * 8;
    unsigned short* dst0 = isA ? &sA[0][0] : &sB[0][0];

    const int l16 = lane & 15, g = lane >> 4;
    const int cswz = ((g ^ ((l16 >> 1) & 3))) * 8;

    if (stager) {
        #pragma unroll
        for (int pt = 0; pt < 2; pt++) {
            #pragma unroll
            for (int i = 0; i < 2; i++)
                GLL16(srcB + (size_t)i * 16 * DD + pt * 32, dst0 + pt * (192 * 32) + (wg + i) * 512);
        }
    }

    #pragma unroll
    for (int t = 0; t < 16; t++) {
        if (t < 15) asm volatile("s_waitcnt vmcnt(2)" ::: "memory");
        else        asm volatile("s_waitcnt vmcnt(0)" ::: "memory");
        __builtin_amdgcn_s_barrier();
        if (t + 2 < 16 && stager) {
            const int buf = (t + 2) % 3;         // compile-time after unroll
            const int k0  = (t + 2) * 32;
            #pragma unroll
            for (int i = 0; i < 2; i++)
                GLL16(srcB + (size_t)i * 16 * DD + k0, dst0 + buf * (192 * 32) + (wg + i) * 512);
        }
        const int cur = t % 3;
        const unsigned short* aBase = &sA[cur][(wsr + l16) * 32 + cswz];
        const unsigned short* bBase = &sB[cur][(wtc + l16) * 32 + cswz];
        bf16x8 af[3];
        #pragma unroll
        for (int mi = 0; mi < 3; mi++) af[mi] = *(const bf16x8*)(aBase + mi * 512);
        __builtin_amdgcn_s_setprio(1);
        #pragma unroll
        for (int ni = 0; ni < 3; ni++) {
            bf16x8 bfr = *(const bf16x8*)(bBase + ni * 512);
            #pragma unroll
            for (int mi = 0; mi < 3; mi++)
                acc[mi][ni] = __builtin_amdgcn_mfma_f32_16x16x32_bf16(af[mi], bfr, acc[mi][ni], 0, 0, 0);
        }
        __builtin_amdgcn_s_setprio(0);
    }

    const int rg = lane >> 4;

    // scale by sigmoid(score_embed)[s][t]
    #pragma unroll
    for (int mi = 0; mi < 3; mi++) {
        #pragma unroll
        for (int r = 0; r < 4; r++) {
            int s = wsr + mi * 16 + rg * 4 + r;
            const float* srow = sig + (size_t)s * SS + wtc;
            #pragma unroll
            for (int ni = 0; ni < 3; ni++)
                acc[mi][ni][r] *= srow[ni * 16 + l16];
        }
    }

    // column max over s (-> maxT indexed by t)
    #pragma unroll
    for (int ni = 0; ni < 3; ni++) {
        float cm = -INFINITY;
        #pragma unroll
        for (int mi = 0; mi < 3; mi++)
            #pragma unroll
            for (int r = 0; r < 4; r++)
                cm = fmaxf(cm, acc[mi][ni][r]);
        cm = fmaxf(cm, __shfl_xor(cm, 16));
        cm = fmaxf(cm, __shfl_xor(cm, 32));
        if (lane < 16) atomicMax(&maxT[wtc + ni * 16 + lane], f2mono(cm));
    }
    // row max over t (-> maxS indexed by s)
    #pragma unroll
    for (int mi = 0; mi < 3; mi++) {
        #pragma unroll
        for (int r = 0; r < 4; r++) {
            float rm = -INFINITY;
            #pragma unroll
            for (int ni = 0; ni < 3; ni++) rm = fmaxf(rm, acc[mi][ni][r]);
            rm = fmaxf(rm, __shfl_xor(rm, 1));
            rm = fmaxf(rm, __shfl_xor(rm, 2));
            rm = fmaxf(rm, __shfl_xor(rm, 4));
            rm = fmaxf(rm, __shfl_xor(rm, 8));
            if ((lane & 15) == 0)
                atomicMax(&maxS[wsr + mi * 16 + rg * 4 + r], f2mono(rm));
        }
    }
    __syncthreads();
    float* out = pooled + (size_t)p * 384;
    if (tid < 192) {
        out[tid]       = mono2f(maxT[tid]);
        out[192 + tid] = mono2f(maxS[tid]);
    }
}

// ---------------- K4: BN1 stats over pooled + pooled->bf16 (for k_w2 GLL path) ----------
__global__ __launch_bounds__(256) void k_bn1(const float* __restrict__ pooled,
                                             float* __restrict__ bn1,
                                             unsigned short* __restrict__ pooledbf) {
    float s = 0.f, ss = 0.f;
    size_t base = (size_t)blockIdx.x * 8192;   // 192 blocks * 8192 = 1572864 exact
    for (int i = 0; i < 32; i++) {
        size_t idx = base + i * 256 + threadIdx.x;
        float v = pooled[idx];
        s += v; ss += v * v;
        pooledbf[idx] = f2bf(v);
    }
    s  = blockReduceSum<4>(s);
    ss = blockReduceSum<4>(ss);
    if (threadIdx.x == 0) { atomicAdd(&bn1[0], s); atomicAdd(&bn1[1], ss); }
}

// ---------------- K5: z = a1*(xbf @ w2bf.T) + c1*rowsumW2 + b2 (bf16) + fused col-stats --
// M=8192, N=2048, K=192 (6 steps of 32). k_proj GLL template, 3-slot counted-vmcnt.
__global__ __launch_bounds__(256) void k_w2(
    const unsigned short* __restrict__ xbf, const unsigned short* __restrict__ w2bf,
    const float* __restrict__ b2, const float* __restrict__ rowsum,
    const float* __restrict__ bn1, const float* __restrict__ g1,
    const float* __restrict__ be1, unsigned short* __restrict__ z,
    float* __restrict__ cs, float* __restrict__ css)
{
    __shared__ unsigned short sA[3][128 * 32];
    __shared__ unsigned short sB[3][128 * 32];
    const int tid = threadIdx.x;
    const int lane = tid & 63;
    const int w = tid >> 6;
    const int m0 = blockIdx.x * 128;
    const int n0 = blockIdx.y * 128;
    const int wm = (w >> 1) * 64, wn = (w & 1) * 64;

    f32x4 acc[4][4] = {};

    const int sr  = lane >> 2;
    const int scg = (lane & 3) ^ ((lane >> 3) & 3);
    const unsigned short* AsrcB = xbf  + (size_t)(m0 + w * 32 + sr) * SS + scg * 8;
    const unsigned short* BsrcB = w2bf + (size_t)(n0 + w * 32 + sr) * SS + scg * 8;

    const int l16 = lane & 15, g = lane >> 4;
    const int cswz = ((g ^ ((l16 >> 1) & 3))) * 8;

    #pragma unroll
    for (int pt = 0; pt < 2; pt++) {
        #pragma unroll
        for (int i = 0; i < 2; i++) {
            int rb = w * 2 + i;
            GLL16(AsrcB + (size_t)i * 16 * SS + pt * 32, &sA[pt][rb * 512]);
            GLL16(BsrcB + (size_t)i * 16 * SS + pt * 32, &sB[pt][rb * 512]);
        }
    }

    #pragma unroll
    for (int t = 0; t < 6; t++) {
        if (t < 5) asm volatile("s_waitcnt vmcnt(4)" ::: "memory");
        else       asm volatile("s_waitcnt vmcnt(0)" ::: "memory");
        __builtin_amdgcn_s_barrier();
        if (t + 2 < 6) {
            const int buf = (t + 2) % 3;
            const int k0  = (t + 2) * 32;
            #pragma unroll
            for (int i = 0; i < 2; i++) {
                int rb = w * 2 + i;
                GLL16(AsrcB + (size_t)i * 16 * SS + k0, &sA[buf][rb * 512]);
                GLL16(BsrcB + (size_t)i * 16 * SS + k0, &sB[buf][rb * 512]);
            }
        }
        const int cur = t % 3;
        const unsigned short* aBase = &sA[cur][(wm + l16) * 32 + cswz];
        const unsigned short* bBase = &sB[cur][(wn + l16) * 32 + cswz];
        bf16x8 af[4];
        #pragma unroll
        for (int mi = 0; mi < 4; mi++) af[mi] = *(const bf16x8*)(aBase + mi * 512);
        __builtin_amdgcn_s_setprio(1);
        #pragma unroll
        for (int ni = 0; ni < 4; ni++) {
            bf16x8 bfr = *(const bf16x8*)(bBase + ni * 512);
            #pragma unroll
            for (int mi = 0; mi < 4; mi++)
                acc[mi][ni] = __builtin_amdgcn_mfma_f32_16x16x32_bf16(af[mi], bfr, acc[mi][ni], 0, 0, 0);
        }
        __builtin_amdgcn_s_setprio(0);
    }

    const float n1 = 8192.0f * 192.0f;
    const float m1 = bn1[0] / n1;
    const float v1 = bn1[1] / n1 - m1 * m1;
    const float a1 = g1[0] * rsqrtf(v1 + EPSV);
    const float c1 = be1[0] - m1 * a1;

    // fused per-column stats: LDS reduce then 1 atomic/col (spread over 4096 addrs)
    float* colsum = (float*)&sA[0][0];         // [128]
    float* colssq = colsum + 128;              // [128]
    __syncthreads();
    if (tid < 128) { colsum[tid] = 0.f; colssq[tid] = 0.f; }
    __syncthreads();

    const int rg = lane >> 4;
    #pragma unroll
    for (int ni = 0; ni < 4; ni++) {
        int lc = wn + ni * 16 + l16;
        int f = n0 + lc;
        float add = c1 * rowsum[f] + b2[f];
        float s_ = 0.f, ss_ = 0.f;
        #pragma unroll
        for (int mi = 0; mi < 4; mi++) {
            #pragma unroll
            for (int r = 0; r < 4; r++) {
                int row = m0 + wm + mi * 16 + rg * 4 + r;
                float y = a1 * acc[mi][ni][r] + add;
                z[(size_t)row * DFF + f] = f2bf(y);
                s_ += y; ss_ += y * y;
            }
        }
        atomicAdd(&colsum[lc], s_);
        atomicAdd(&colssq[lc], ss_);
    }
    __syncthreads();
    if (tid < 128) {
        atomicAdd(&cs[n0 + tid],  colsum[tid]);
        atomicAdd(&css[n0 + tid], colssq[tid]);
    }
}

// ---------------- K7: rowout = relu(BN2(z)) . W3 + b3  (wave per row, coef inline) -------
__global__ __launch_bounds__(256) void k_final_dot(
    const unsigned short* __restrict__ z, const float* __restrict__ cs,
    const float* __restrict__ css, const float* __restrict__ g2,
    const float* __restrict__ be2, const float* __restrict__ W3,
    const float* __restrict__ b3, float* __restrict__ rowout)
{
    const int lane = threadIdx.x & 63, w = threadIdx.x >> 6;
    float4 av[4][2], cv[4][2], wv[4][2];
    #pragma unroll
    for (int c = 0; c < 4; c++) {
        int col = c * 512 + lane * 8;
        #pragma unroll
        for (int h = 0; h < 2; h++) {
            float4 csv  = *(const float4*)(cs  + col + 4*h);
            float4 cssv = *(const float4*)(css + col + 4*h);
            float4 g2v  = *(const float4*)(g2  + col + 4*h);
            float4 be2v = *(const float4*)(be2 + col + 4*h);
            wv[c][h]    = *(const float4*)(W3  + col + 4*h);
            float* mp = (float*)&csv; float* sp = (float*)&cssv;
            float* gp = (float*)&g2v; float* bp = (float*)&be2v;
            float* ap = (float*)&av[c][h]; float* cp = (float*)&cv[c][h];
            #pragma unroll
            for (int j = 0; j < 4; j++) {
                float m  = mp[j] * (1.0f / 8192.0f);
                float vr = sp[j] * (1.0f / 8192.0f) - m * m;
                float a  = gp[j] * rsqrtf(vr + EPSV);
                ap[j] = a;
                cp[j] = bp[j] - m * a;
            }
        }
    }
    const float bias = b3[0];
    int r0 = blockIdx.x * 16 + w * 4;          // 512 blocks
    #pragma unroll
    for (int rr = 0; rr < 4; rr++) {
        int row = r0 + rr;
        float sum = 0.f;
        #pragma unroll
        for (int c = 0; c < 4; c++) {
            uint4 v = *(const uint4*)(z + (size_t)row * DFF + c * 512 + lane * 8);
            unsigned short pv[8];
            *(uint4*)pv = v;
            #pragma unroll
            for (int j = 0; j < 8; j++) {
                float a = ((const float*)&av[c][j >> 2])[j & 3];
                float cc = ((const float*)&cv[c][j >> 2])[j & 3];
                float wf = ((const float*)&wv[c][j >> 2])[j & 3];
                float x = a * bf2f(pv[j]) + cc;
                sum += fmaxf(x, 0.f) * wf;
            }
        }
        #pragma unroll
        for (int o = 32; o > 0; o >>= 1) sum += __shfl_down(sum, o);
        if (lane == 0) rowout[row] = sum + bias;
    }
}

// ---------------- K8: pair-sum + BN3 + output ----------------
__global__ __launch_bounds__(1024) void k_out(
    const float* __restrict__ rowout, const float* __restrict__ g3,
    const float* __restrict__ be3, float* __restrict__ out)
{
    float pv0, pv1, pv2, pv3;
    float s = 0.f, ss = 0.f;
    {
        int p0 = threadIdx.x;
        pv0 = rowout[2*p0] + rowout[2*p0+1];
        int p1 = 1024 + threadIdx.x;
        pv1 = rowout[2*p1] + rowout[2*p1+1];
        int p2 = 2048 + threadIdx.x;
        pv2 = rowout[2*p2] + rowout[2*p2+1];
        int p3 = 3072 + threadIdx.x;
        pv3 = rowout[2*p3] + rowout[2*p3+1];
        s = pv0 + pv1 + pv2 + pv3;
        ss = pv0*pv0 + pv1*pv1 + pv2*pv2 + pv3*pv3;
    }
    s  = blockReduceSum<16>(s);
    ss = blockReduceSum<16>(ss);
    float m  = s * (1.0f / 4096.0f);
    float vr = ss * (1.0f / 4096.0f) - m * m;
    float a  = g3[0] * rsqrtf(vr + EPSV);
    float c  = be3[0] - m * a;
    out[threadIdx.x]        = a * pv0 + c;
    out[1024 + threadIdx.x] = a * pv1 + c;
    out[2048 + threadIdx.x] = a * pv2 + c;
    out[3072 + threadIdx.x] = a * pv3 + c;
}

extern "C" void kernel_launch(void* const* d_in, const int* in_sizes, int n_in,
                              void* d_out, int out_size, void* d_ws, size_t ws_size,
                              hipStream_t stream)
{
    const float* tgt = (const float*)d_in[0];
    const float* mem = (const float*)d_in[1];
    const float* W1  = (const float*)d_in[2];
    const float* b1  = (const float*)d_in[3];
    const float* se  = (const float*)d_in[4];
    const float* g1  = (const float*)d_in[5];
    const float* be1 = (const float*)d_in[6];
    const float* W2  = (const float*)d_in[7];
    const float* b2  = (const float*)d_in[8];
    const float* g2  = (const float*)d_in[9];
    const float* be2 = (const float*)d_in[10];
    const float* W3  = (const float*)d_in[11];
    const float* b3  = (const float*)d_in[12];
    const float* g3  = (const float*)d_in[13];
    const float* be3 = (const float*)d_in[14];
    float* out = (float*)d_out;

    char* ws = (char*)d_ws;
    size_t off = 0;
    auto alloc = [&](size_t bytes) { void* p = ws + off; off += (bytes + 255) & ~(size_t)255; return p; };

    // region0: xbf (25.2 MB, used by k_proj) then reused as z (33.5 MB, from k_w2 on)
    char* region0 = (char*)alloc((size_t)8192 * DFF * 2);                  // 33.5 MB
    unsigned short* xbf = (unsigned short*)region0;                        // [24576][512] bf16
    unsigned short* z   = (unsigned short*)region0;                        // [8192][2048] bf16
    unsigned short* qk  = (unsigned short*)alloc((size_t)24576 * DD * 2);  // 25.2 MB (query | key)
    unsigned short* w1bf= (unsigned short*)alloc((size_t)DD * DD * 2);     // 0.5 MB
    unsigned short* w2bf= (unsigned short*)alloc((size_t)DFF * SS * 2);    // 0.8 MB
    float* sig          = (float*)alloc((size_t)SS * SS * 4);
    float* pooled       = (float*)alloc((size_t)4096 * 384 * 4);           // 6.3 MB
    unsigned short* pooledbf = (unsigned short*)alloc((size_t)4096 * 384 * 2); // 3.1 MB
    float* rowsum       = (float*)alloc(DFF * 4);
    float* stats        = (float*)alloc((2 + 2 * DFF) * 4);                // bn1[2], cs[2048], css[2048]
    float* rowout       = (float*)alloc(8192 * 4);

    float* bn1 = stats;
    float* cs  = stats + 2;
    float* css = stats + 2 + DFF;

    hipMemsetAsync(stats, 0, (2 + 2 * DFF) * 4, stream);

    k_cvt2<<<12288, 256, 0, stream>>>(tgt, mem, xbf);
    k_prep<<<792, 256, 0, stream>>>(W1, se, W2, w1bf, sig, rowsum, w2bf);
    k_proj<<<dim3(192, 4), 256, 0, stream>>>(xbf, w1bf, b1, qk);
    k_score<<<4096, 1024, 0, stream>>>(qk, qk + (size_t)NROW * DD, sig, pooled);
    k_bn1<<<192, 256, 0, stream>>>(pooled, bn1, pooledbf);
    k_w2<<<dim3(64, 16), 256, 0, stream>>>(pooledbf, w2bf, b2, rowsum, bn1, g1, be1, z, cs, css);
    k_final_dot<<<512, 256, 0, stream>>>(z, cs, css, g2, be2, W3, b3, rowout);
    k_out<<<1, 1024, 0, stream>>>(rowout, g3, be3, out);
}

// Round 16
// 311.771 us; speedup vs baseline: 1.5776x; 1.0101x over previous
//
#include <hip/hip_runtime.h>

#define SS 192
#define DD 512
#define DFF 2048
#define NROW 12288            // 64*192 rows per tensor
#define EPSV 1e-5f

using bf16x8 = __attribute__((ext_vector_type(8))) __bf16;
using f32x4  = __attribute__((ext_vector_type(4))) float;

__device__ inline unsigned short f2bf(float f) {
    unsigned u = __float_as_uint(f);
    unsigned r = (u + 0x7FFFu + ((u >> 16) & 1u)) >> 16;
    return (unsigned short)r;
}
__device__ inline float bf2f(unsigned short h) {
    return __uint_as_float(((unsigned)h) << 16);
}
// monotonic float<->uint for atomicMax on floats (incl. negatives)
__device__ inline unsigned f2mono(float f) {
    unsigned u = __float_as_uint(f);
    return u ^ ((unsigned)((int)u >> 31) | 0x80000000u);
}
__device__ inline float mono2f(unsigned u) {
    unsigned b = (u & 0x80000000u) ? (u ^ 0x80000000u) : ~u;
    return __uint_as_float(b);
}
#define ENC_NEGINF 0x007FFFFFu

// async global->LDS, 16B per lane. dst must be wave-uniform; src is per-lane.
#define GLL16(g, l) __builtin_amdgcn_global_load_lds( \
    (const __attribute__((address_space(1))) void*)(g), \
    (__attribute__((address_space(3))) void*)(l), 16, 0, 0)

template<int NW>
__device__ inline float blockReduceSum(float v) {
    __shared__ float red[NW];
    #pragma unroll
    for (int o = 32; o > 0; o >>= 1) v += __shfl_down(v, o);
    int w = threadIdx.x >> 6;
    __syncthreads();
    if ((threadIdx.x & 63) == 0) red[w] = v;
    __syncthreads();
    if (threadIdx.x == 0) {
        float t = 0;
        #pragma unroll
        for (int i = 0; i < NW; i++) t += red[i];
        red[0] = t;
    }
    __syncthreads();
    return red[0];
}

// ---------------- K0: tgt+mem f32 -> bf16 (one launch) ----------------
__global__ void k_cvt2(const float* __restrict__ a, const float* __restrict__ b,
                       unsigned short* __restrict__ dst) {
    int i = blockIdx.x * 256 + threadIdx.x;        // grid 12288 -> 3145728 quads
    const int half = NROW * DD / 4;                 // tgt quads
    const float* src = (i < half) ? a : b;
    int j = (i < half) ? i : i - half;
    float4 v = ((const float4*)src)[j];
    unsigned short o[4] = { f2bf(v.x), f2bf(v.y), f2bf(v.z), f2bf(v.w) };
    ((uint2*)dst)[i] = *(uint2*)o;
}

// ---------------- K1p: prep (W1 cvt | sigmoid | W2 rowsum | W2 cvt) one launch ---------
__global__ void k_prep(const float* __restrict__ W1, const float* __restrict__ se,
                       const float* __restrict__ W2,
                       unsigned short* __restrict__ w1bf, float* __restrict__ sig,
                       float* __restrict__ rowsum, unsigned short* __restrict__ w2bf) {
    int bid = blockIdx.x;
    if (bid < 256) {                                // W1: 262144 elems / 1024 = 256 blocks
        int i = bid * 256 + threadIdx.x;
        float4 v = ((const float4*)W1)[i];
        unsigned short o[4] = { f2bf(v.x), f2bf(v.y), f2bf(v.z), f2bf(v.w) };
        ((uint2*)w1bf)[i] = *(uint2*)o;
    } else if (bid < 400) {                         // sig: 36864 / 256 = 144 blocks
        int i = (bid - 256) * 256 + threadIdx.x;
        sig[i] = 1.0f / (1.0f + __expf(-se[i]));
    } else if (bid < 408) {                         // rowsum: 8 blocks
        int f = (bid - 400) * 256 + threadIdx.x;
        float s = 0.f;
        for (int i = 0; i < SS; i++) s += W2[(size_t)f * SS + i];
        rowsum[f] = s;
    } else {                                        // W2: 393216 elems / 1024 = 384 blocks
        int i = (bid - 408) * 256 + threadIdx.x;
        float4 v = ((const float4*)W2)[i];
        unsigned short o[4] = { f2bf(v.x), f2bf(v.y), f2bf(v.z), f2bf(v.w) };
        ((uint2*)w2bf)[i] = *(uint2*)o;
    }
}

// ---------------- K1: projection GEMM  P = Xbf @ W1bf.T + b1 -> bf16 ----------------
// M=24576, N=512, K=512. tile 128x128, BK=32. 3-buffer counted-vmcnt, FULLY UNROLLED.
__global__ __launch_bounds__(256) void k_proj(
    const unsigned short* __restrict__ xbf, const unsigned short* __restrict__ w1bf,
    const float* __restrict__ b1, unsigned short* __restrict__ outQK)
{
    __shared__ unsigned short sA[3][128 * 32];
    __shared__ unsigned short sB[3][128 * 32];
    const int tid = threadIdx.x;
    const int lane = tid & 63;
    const int w = tid >> 6;
    const int m0 = blockIdx.x * 128;
    const int n0 = blockIdx.y * 128;
    const int wm = (w >> 1) * 64, wn = (w & 1) * 64;

    f32x4 acc[4][4] = {};

    const int sr  = lane >> 2;                            // row within 16-block
    const int scg = (lane & 3) ^ ((lane >> 3) & 3);       // swizzled src colgroup
    const unsigned short* Ab = xbf  + (size_t)m0 * DD;
    const unsigned short* Bb = w1bf + (size_t)n0 * DD;
    const unsigned short* AsrcB = Ab + (size_t)(w * 2 * 16 + sr) * DD + scg * 8;
    const unsigned short* BsrcB = Bb + (size_t)(w * 2 * 16 + sr) * DD + scg * 8;

    const int l16 = lane & 15, g = lane >> 4;
    const int cswz = ((g ^ ((l16 >> 1) & 3))) * 8;        // shorts

    #pragma unroll
    for (int pt = 0; pt < 2; pt++) {
        #pragma unroll
        for (int i = 0; i < 2; i++) {
            int rb = w * 2 + i;
            GLL16(AsrcB + (size_t)i * 16 * DD + pt * 32, &sA[pt][rb * 512]);
            GLL16(BsrcB + (size_t)i * 16 * DD + pt * 32, &sB[pt][rb * 512]);
        }
    }

    #pragma unroll
    for (int t = 0; t < 16; t++) {
        if (t < 15) asm volatile("s_waitcnt vmcnt(4)" ::: "memory");
        else        asm volatile("s_waitcnt vmcnt(0)" ::: "memory");
        __builtin_amdgcn_s_barrier();
        if (t + 2 < 16) {
            const int buf = (t + 2) % 3;       // compile-time after unroll
            const int k0  = (t + 2) * 32;
            #pragma unroll
            for (int i = 0; i < 2; i++) {
                int rb = w * 2 + i;
                GLL16(AsrcB + (size_t)i * 16 * DD + k0, &sA[buf][rb * 512]);
                GLL16(BsrcB + (size_t)i * 16 * DD + k0, &sB[buf][rb * 512]);
            }
        }
        const int cur = t % 3;
        const unsigned short* aBase = &sA[cur][(wm + l16) * 32 + cswz];
        const unsigned short* bBase = &sB[cur][(wn + l16) * 32 + cswz];
        bf16x8 af[4];
        #pragma unroll
        for (int mi = 0; mi < 4; mi++) af[mi] = *(const bf16x8*)(aBase + mi * 512);
        __builtin_amdgcn_s_setprio(1);
        #pragma unroll
        for (int ni = 0; ni < 4; ni++) {
            bf16x8 bfr = *(const bf16x8*)(bBase + ni * 512);
            #pragma unroll
            for (int mi = 0; mi < 4; mi++)
                acc[mi][ni] = __builtin_amdgcn_mfma_f32_16x16x32_bf16(af[mi], bfr, acc[mi][ni], 0, 0, 0);
        }
        __builtin_amdgcn_s_setprio(0);
    }

    const int rg = lane >> 4;
    #pragma unroll
    for (int ni = 0; ni < 4; ni++) {
        int e = n0 + wn + ni * 16 + l16;
        float bias = b1[e];
        #pragma unroll
        for (int mi = 0; mi < 4; mi++) {
            #pragma unroll
            for (int r = 0; r < 4; r++) {
                int row = m0 + wm + mi * 16 + rg * 4 + r;
                outQK[(size_t)row * DD + e] = f2bf(acc[mi][ni][r] + bias);
            }
        }
    }
}

// ---------------- K3: per-(q,k) score tile + sigmoid scale + dual max-pool ----------------
// 16 waves (1024 thr), wave tile 48x48 (acc[3][3]=36 AGPR, 4 waves/SIMD). 3-slot
// counted-vmcnt pipeline (R7-proven, pristine). No BN1 fusion (atomics serialize).
__global__ __launch_bounds__(1024, 4) void k_score(
    const unsigned short* __restrict__ qB,
    const unsigned short* __restrict__ kB,
    const float* __restrict__ sig,
    float* __restrict__ pooled)
{
    __shared__ unsigned short sA[3][192 * 32];   // key rows (s)
    __shared__ unsigned short sB[3][192 * 32];   // query rows (t)
    __shared__ unsigned maxT[192];
    __shared__ unsigned maxS[192];

    const int tid = threadIdx.x;
    const int p = blockIdx.x;
    const int q = p >> 6, kk = p & 63;
    const unsigned short* Ab = kB + (size_t)kk * SS * DD;
    const unsigned short* Bb = qB + (size_t)q * SS * DD;

    if (tid < 192) { maxT[tid] = ENC_NEGINF; maxS[tid] = ENC_NEGINF; }

    const int lane = tid & 63, w = tid >> 6;     // w = 0..15
    const int wsr = (w >> 2) * 48;   // wave s-offset: 0,48,96,144
    const int wtc = (w & 3) * 48;    // wave t-offset: 0,48,96,144

    f32x4 acc[3][3] = {};

    const int sr  = lane >> 2;
    const int scg = (lane & 3) ^ ((lane >> 3) & 3);
    const bool stager = (w < 12);
    const bool isA = (w < 6);
    const int wg = (isA ? w : (w - 6)) * 2;      // first row-group (0,2,..,10)
    const unsigned short* srcB = (isA ? Ab : Bb) + (size_t)(wg * 16 + sr) * DD + scg * 8;
    unsigned short* dst0 = isA ? &sA[0][0] : &sB[0][0];

    const int l16 = lane & 15, g = lane >> 4;
    const int cswz = ((g ^ ((l16 >> 1) & 3))) * 8;

    if (stager) {
        #pragma unroll
        for (int pt = 0; pt < 2; pt++) {
            #pragma unroll
            for (int i = 0; i < 2; i++)
                GLL16(srcB + (size_t)i * 16 * DD + pt * 32, dst0 + pt * (192 * 32) + (wg + i) * 512);
        }
    }

    #pragma unroll
    for (int t = 0; t < 16; t++) {
        if (t < 15) asm volatile("s_waitcnt vmcnt(2)" ::: "memory");
        else        asm volatile("s_waitcnt vmcnt(0)" ::: "memory");
        __builtin_amdgcn_s_barrier();
        if (t + 2 < 16 && stager) {
            const int buf = (t + 2) % 3;         // compile-time after unroll
            const int k0  = (t + 2) * 32;
            #pragma unroll
            for (int i = 0; i < 2; i++)
                GLL16(srcB + (size_t)i * 16 * DD + k0, dst0 + buf * (192 * 32) + (wg + i) * 512);
        }
        const int cur = t % 3;
        const unsigned short* aBase = &sA[cur][(wsr + l16) * 32 + cswz];
        const unsigned short* bBase = &sB[cur][(wtc + l16) * 32 + cswz];
        bf16x8 af[3];
        #pragma unroll
        for (int mi = 0; mi < 3; mi++) af[mi] = *(const bf16x8*)(aBase + mi * 512);
        __builtin_amdgcn_s_setprio(1);
        #pragma unroll
        for (int ni = 0; ni < 3; ni++) {
            bf16x8 bfr = *(const bf16x8*)(bBase + ni * 512);
            #pragma unroll
            for (int mi = 0; mi < 3; mi++)
                acc[mi][ni] = __builtin_amdgcn_mfma_f32_16x16x32_bf16(af[mi], bfr, acc[mi][ni], 0, 0, 0);
        }
        __builtin_amdgcn_s_setprio(0);
    }

    const int rg = lane >> 4;

    // scale by sigmoid(score_embed)[s][t]
    #pragma unroll
    for (int mi = 0; mi < 3; mi++) {
        #pragma unroll
        for (int r = 0; r < 4; r++) {
            int s = wsr + mi * 16 + rg * 4 + r;
            const float* srow = sig + (size_t)s * SS + wtc;
            #pragma unroll
            for (int ni = 0; ni < 3; ni++)
                acc[mi][ni][r] *= srow[ni * 16 + l16];
        }
    }

    // column max over s (-> maxT indexed by t)
    #pragma unroll
    for (int ni = 0; ni < 3; ni++) {
        float cm = -INFINITY;
        #pragma unroll
        for (int mi = 0; mi < 3; mi++)
            #pragma unroll
            for (int r = 0; r < 4; r++)
                cm = fmaxf(cm, acc[mi][ni][r]);
        cm = fmaxf(cm, __shfl_xor(cm, 16));
        cm = fmaxf(cm, __shfl_xor(cm, 32));
        if (lane < 16) atomicMax(&maxT[wtc + ni * 16 + lane], f2mono(cm));
    }
    // row max over t (-> maxS indexed by s)
    #pragma unroll
    for (int mi = 0; mi < 3; mi++) {
        #pragma unroll
        for (int r = 0; r < 4; r++) {
            float rm = -INFINITY;
            #pragma unroll
            for (int ni = 0; ni < 3; ni++) rm = fmaxf(rm, acc[mi][ni][r]);
            rm = fmaxf(rm, __shfl_xor(rm, 1));
            rm = fmaxf(rm, __shfl_xor(rm, 2));
            rm = fmaxf(rm, __shfl_xor(rm, 4));
            rm = fmaxf(rm, __shfl_xor(rm, 8));
            if ((lane & 15) == 0)
                atomicMax(&maxS[wsr + mi * 16 + rg * 4 + r], f2mono(rm));
        }
    }
    __syncthreads();
    float* out = pooled + (size_t)p * 384;
    if (tid < 192) {
        out[tid]       = mono2f(maxT[tid]);
        out[192 + tid] = mono2f(maxS[tid]);
    }
}

// ---------------- K4: BN1 stats over pooled + pooled->bf16 (for k_w2 GLL path) ----------
__global__ __launch_bounds__(256) void k_bn1(const float* __restrict__ pooled,
                                             float* __restrict__ bn1,
                                             unsigned short* __restrict__ pooledbf) {
    float s = 0.f, ss = 0.f;
    size_t base = (size_t)blockIdx.x * 8192;   // 192 blocks * 8192 = 1572864 exact
    for (int i = 0; i < 32; i++) {
        size_t idx = base + i * 256 + threadIdx.x;
        float v = pooled[idx];
        s += v; ss += v * v;
        pooledbf[idx] = f2bf(v);
    }
    s  = blockReduceSum<4>(s);
    ss = blockReduceSum<4>(ss);
    if (threadIdx.x == 0) { atomicAdd(&bn1[0], s); atomicAdd(&bn1[1], ss); }
}

// ---------------- K5: z = a1*(xbf @ w2bf.T) + c1*rowsumW2 + b2 (bf16) + fused col-stats --
// M=8192, N=2048, K=192 (6 steps of 32). k_proj GLL template, 3-slot counted-vmcnt.
__global__ __launch_bounds__(256) void k_w2(
    const unsigned short* __restrict__ xbf, const unsigned short* __restrict__ w2bf,
    const float* __restrict__ b2, const float* __restrict__ rowsum,
    const float* __restrict__ bn1, const float* __restrict__ g1,
    const float* __restrict__ be1, unsigned short* __restrict__ z,
    float* __restrict__ cs, float* __restrict__ css)
{
    __shared__ unsigned short sA[3][128 * 32];
    __shared__ unsigned short sB[3][128 * 32];
    const int tid = threadIdx.x;
    const int lane = tid & 63;
    const int w = tid >> 6;
    const int m0 = blockIdx.x * 128;
    const int n0 = blockIdx.y * 128;
    const int wm = (w >> 1) * 64, wn = (w & 1) * 64;

    f32x4 acc[4][4] = {};

    const int sr  = lane >> 2;
    const int scg = (lane & 3) ^ ((lane >> 3) & 3);
    const unsigned short* AsrcB = xbf  + (size_t)(m0 + w * 32 + sr) * SS + scg * 8;
    const unsigned short* BsrcB = w2bf + (size_t)(n0 + w * 32 + sr) * SS + scg * 8;

    const int l16 = lane & 15, g = lane >> 4;
    const int cswz = ((g ^ ((l16 >> 1) & 3))) * 8;

    #pragma unroll
    for (int pt = 0; pt < 2; pt++) {
        #pragma unroll
        for (int i = 0; i < 2; i++) {
            int rb = w * 2 + i;
            GLL16(AsrcB + (size_t)i * 16 * SS + pt * 32, &sA[pt][rb * 512]);
            GLL16(BsrcB + (size_t)i * 16 * SS + pt * 32, &sB[pt][rb * 512]);
        }
    }

    #pragma unroll
    for (int t = 0; t < 6; t++) {
        if (t < 5) asm volatile("s_waitcnt vmcnt(4)" ::: "memory");
        else       asm volatile("s_waitcnt vmcnt(0)" ::: "memory");
        __builtin_amdgcn_s_barrier();
        if (t + 2 < 6) {
            const int buf = (t + 2) % 3;
            const int k0  = (t + 2) * 32;
            #pragma unroll
            for (int i = 0; i < 2; i++) {
                int rb = w * 2 + i;
                GLL16(AsrcB + (size_t)i * 16 * SS + k0, &sA[buf][rb * 512]);
                GLL16(BsrcB + (size_t)i * 16 * SS + k0, &sB[buf][rb * 512]);
            }
        }
        const int cur = t % 3;
        const unsigned short* aBase = &sA[cur][(wm + l16) * 32 + cswz];
        const unsigned short* bBase = &sB[cur][(wn + l16) * 32 + cswz];
        bf16x8 af[4];
        #pragma unroll
        for (int mi = 0; mi < 4; mi++) af[mi] = *(const bf16x8*)(aBase + mi * 512);
        __builtin_amdgcn_s_setprio(1);
        #pragma unroll
        for (int ni = 0; ni < 4; ni++) {
            bf16x8 bfr = *(const bf16x8*)(bBase + ni * 512);
            #pragma unroll
            for (int mi = 0; mi < 4; mi++)
                acc[mi][ni] = __builtin_amdgcn_mfma_f32_16x16x32_bf16(af[mi], bfr, acc[mi][ni], 0, 0, 0);
        }
        __builtin_amdgcn_s_setprio(0);
    }

    const float n1 = 8192.0f * 192.0f;
    const float m1 = bn1[0] / n1;
    const float v1 = bn1[1] / n1 - m1 * m1;
    const float a1 = g1[0] * rsqrtf(v1 + EPSV);
    const float c1 = be1[0] - m1 * a1;

    // fused per-column stats: LDS reduce then 1 atomic/col (spread over 4096 addrs)
    float* colsum = (float*)&sA[0][0];         // [128]
    float* colssq = colsum + 128;              // [128]
    __syncthreads();
    if (tid < 128) { colsum[tid] = 0.f; colssq[tid] = 0.f; }
    __syncthreads();

    const int rg = lane >> 4;
    #pragma unroll
    for (int ni = 0; ni < 4; ni++) {
        int lc = wn + ni * 16 + l16;
        int f = n0 + lc;
        float add = c1 * rowsum[f] + b2[f];
        float s_ = 0.f, ss_ = 0.f;
        #pragma unroll
        for (int mi = 0; mi < 4; mi++) {
            #pragma unroll
            for (int r = 0; r < 4; r++) {
                int row = m0 + wm + mi * 16 + rg * 4 + r;
                float y = a1 * acc[mi][ni][r] + add;
                z[(size_t)row * DFF + f] = f2bf(y);
                s_ += y; ss_ += y * y;
            }
        }
        atomicAdd(&colsum[lc], s_);
        atomicAdd(&colssq[lc], ss_);
    }
    __syncthreads();
    if (tid < 128) {
        atomicAdd(&cs[n0 + tid],  colsum[tid]);
        atomicAdd(&css[n0 + tid], colssq[tid]);
    }
}

// ---------------- K7: rowout = relu(BN2(z)) . W3 + b3  (wave per row, coef inline) -------
__global__ __launch_bounds__(256) void k_final_dot(
    const unsigned short* __restrict__ z, const float* __restrict__ cs,
    const float* __restrict__ css, const float* __restrict__ g2,
    const float* __restrict__ be2, const float* __restrict__ W3,
    const float* __restrict__ b3, float* __restrict__ rowout)
{
    const int lane = threadIdx.x & 63, w = threadIdx.x >> 6;
    float4 av[4][2], cv[4][2], wv[4][2];
    #pragma unroll
    for (int c = 0; c < 4; c++) {
        int col = c * 512 + lane * 8;
        #pragma unroll
        for (int h = 0; h < 2; h++) {
            float4 csv  = *(const float4*)(cs  + col + 4*h);
            float4 cssv = *(const float4*)(css + col + 4*h);
            float4 g2v  = *(const float4*)(g2  + col + 4*h);
            float4 be2v = *(const float4*)(be2 + col + 4*h);
            wv[c][h]    = *(const float4*)(W3  + col + 4*h);
            float* mp = (float*)&csv; float* sp = (float*)&cssv;
            float* gp = (float*)&g2v; float* bp = (float*)&be2v;
            float* ap = (float*)&av[c][h]; float* cp = (float*)&cv[c][h];
            #pragma unroll
            for (int j = 0; j < 4; j++) {
                float m  = mp[j] * (1.0f / 8192.0f);
                float vr = sp[j] * (1.0f / 8192.0f) - m * m;
                float a  = gp[j] * rsqrtf(vr + EPSV);
                ap[j] = a;
                cp[j] = bp[j] - m * a;
            }
        }
    }
    const float bias = b3[0];
    int r0 = blockIdx.x * 16 + w * 4;          // 512 blocks
    #pragma unroll
    for (int rr = 0; rr < 4; rr++) {
        int row = r0 + rr;
        float sum = 0.f;
        #pragma unroll
        for (int c = 0; c < 4; c++) {
            uint4 v = *(const uint4*)(z + (size_t)row * DFF + c * 512 + lane * 8);
            unsigned short pv[8];
            *(uint4*)pv = v;
            #pragma unroll
            for (int j = 0; j < 8; j++) {
                float a = ((const float*)&av[c][j >> 2])[j & 3];
                float cc = ((const float*)&cv[c][j >> 2])[j & 3];
                float wf = ((const float*)&wv[c][j >> 2])[j & 3];
                float x = a * bf2f(pv[j]) + cc;
                sum += fmaxf(x, 0.f) * wf;
            }
        }
        #pragma unroll
        for (int o = 32; o > 0; o >>= 1) sum += __shfl_down(sum, o);
        if (lane == 0) rowout[row] = sum + bias;
    }
}

// ---------------- K8: pair-sum + BN3 + output ----------------
__global__ __launch_bounds__(1024) void k_out(
    const float* __restrict__ rowout, const float* __restrict__ g3,
    const float* __restrict__ be3, float* __restrict__ out)
{
    float pv0, pv1, pv2, pv3;
    float s = 0.f, ss = 0.f;
    {
        int p0 = threadIdx.x;
        pv0 = rowout[2*p0] + rowout[2*p0+1];
        int p1 = 1024 + threadIdx.x;
        pv1 = rowout[2*p1] + rowout[2*p1+1];
        int p2 = 2048 + threadIdx.x;
        pv2 = rowout[2*p2] + rowout[2*p2+1];
        int p3 = 3072 + threadIdx.x;
        pv3 = rowout[2*p3] + rowout[2*p3+1];
        s = pv0 + pv1 + pv2 + pv3;
        ss = pv0*pv0 + pv1*pv1 + pv2*pv2 + pv3*pv3;
    }
    s  = blockReduceSum<16>(s);
    ss = blockReduceSum<16>(ss);
    float m  = s * (1.0f / 4096.0f);
    float vr = ss * (1.0f / 4096.0f) - m * m;
    float a  = g3[0] * rsqrtf(vr + EPSV);
    float c  = be3[0] - m * a;
    out[threadIdx.x]        = a * pv0 + c;
    out[1024 + threadIdx.x] = a * pv1 + c;
    out[2048 + threadIdx.x] = a * pv2 + c;
    out[3072 + threadIdx.x] = a * pv3 + c;
}

extern "C" void kernel_launch(void* const* d_in, const int* in_sizes, int n_in,
                              void* d_out, int out_size, void* d_ws, size_t ws_size,
                              hipStream_t stream)
{
    const float* tgt = (const float*)d_in[0];
    const float* mem = (const float*)d_in[1];
    const float* W1  = (const float*)d_in[2];
    const float* b1  = (const float*)d_in[3];
    const float* se  = (const float*)d_in[4];
    const float* g1  = (const float*)d_in[5];
    const float* be1 = (const float*)d_in[6];
    const float* W2  = (const float*)d_in[7];
    const float* b2  = (const float*)d_in[8];
    const float* g2  = (const float*)d_in[9];
    const float* be2 = (const float*)d_in[10];
    const float* W3  = (const float*)d_in[11];
    const float* b3  = (const float*)d_in[12];
    const float* g3  = (const float*)d_in[13];
    const float* be3 = (const float*)d_in[14];
    float* out = (float*)d_out;

    char* ws = (char*)d_ws;
    size_t off = 0;
    auto alloc = [&](size_t bytes) { void* p = ws + off; off += (bytes + 255) & ~(size_t)255; return p; };

    // region0: xbf (25.2 MB, used by k_proj) then reused as z (33.5 MB, from k_w2 on)
    char* region0 = (char*)alloc((size_t)8192 * DFF * 2);                  // 33.5 MB
    unsigned short* xbf = (unsigned short*)region0;                        // [24576][512] bf16
    unsigned short* z   = (unsigned short*)region0;                        // [8192][2048] bf16
    unsigned short* qk  = (unsigned short*)alloc((size_t)24576 * DD * 2);  // 25.2 MB (query | key)
    unsigned short* w1bf= (unsigned short*)alloc((size_t)DD * DD * 2);     // 0.5 MB
    unsigned short* w2bf= (unsigned short*)alloc((size_t)DFF * SS * 2);    // 0.8 MB
    float* sig          = (float*)alloc((size_t)SS * SS * 4);
    float* pooled       = (float*)alloc((size_t)4096 * 384 * 4);           // 6.3 MB
    unsigned short* pooledbf = (unsigned short*)alloc((size_t)4096 * 384 * 2); // 3.1 MB
    float* rowsum       = (float*)alloc(DFF * 4);
    float* stats        = (float*)alloc((2 + 2 * DFF) * 4);                // bn1[2], cs[2048], css[2048]
    float* rowout       = (float*)alloc(8192 * 4);

    float* bn1 = stats;
    float* cs  = stats + 2;
    float* css = stats + 2 + DFF;

    hipMemsetAsync(stats, 0, (2 + 2 * DFF) * 4, stream);

    k_cvt2<<<12288, 256, 0, stream>>>(tgt, mem, xbf);
    k_prep<<<792, 256, 0, stream>>>(W1, se, W2, w1bf, sig, rowsum, w2bf);
    k_proj<<<dim3(192, 4), 256, 0, stream>>>(xbf, w1bf, b1, qk);
    k_score<<<4096, 1024, 0, stream>>>(qk, qk + (size_t)NROW * DD, sig, pooled);
    k_bn1<<<192, 256, 0, stream>>>(pooled, bn1, pooledbf);
    k_w2<<<dim3(64, 16), 256, 0, stream>>>(pooledbf, w2bf, b2, rowsum, bn1, g1, be1, z, cs, css);
    k_final_dot<<<512, 256, 0, stream>>>(z, cs, css, g2, be2, W3, b3, rowout);
    k_out<<<1, 1024, 0, stream>>>(rowout, g3, be3, out);
}